// Round 8
// baseline (7263.935 us; speedup 1.0000x reference)
//
#include <hip/hip_runtime.h>
#include <math.h>

// Problem constants
#define HH   300
#define H3   900
#define MMOL 256
#define LATM 128
#define AA   32769        // 1 + 256*128
#define NBB  6
#define BBND 131073       // 1 + 4*256*128
#define AFD  133
#define BFD  147
#define MLR  (MMOL * LATM)   // 32768

static __device__ __forceinline__ float sigm(float x) { return 1.0f / (1.0f + expf(-x)); }

// ---------------------------------------------------------------------------
// gemm_w: 128x128 tile, BK=16, 8x8 microtile, 256 threads.
// C[r, ldc] = act( X[r, ldx] @ Wrow(n)=W[n*ldw..]  (+Bias) (+=C) )
// ---------------------------------------------------------------------------
template<bool RELU, bool BIAS, bool ACCUM>
__global__ __launch_bounds__(256)
void gemm_w(const float* __restrict__ X, int ldx, const float* __restrict__ W, int ldw,
            const float* __restrict__ Bias, float* __restrict__ C, int ldc,
            int rows, int N, int K)
{
    __shared__ float Xs[16][132];
    __shared__ float Ws[16][132];
    const int row0 = blockIdx.x * 128;
    const int col0 = blockIdx.y * 128;
    const int tid  = threadIdx.x;
    const int tm   = (tid >> 4) * 8;
    const int tn   = (tid & 15) * 8;
    const bool xv  = ((ldx & 3) == 0);
    const bool wv  = ((ldw & 3) == 0);

    float acc[8][8];
#pragma unroll
    for (int i = 0; i < 8; ++i)
#pragma unroll
        for (int j = 0; j < 8; ++j) acc[i][j] = 0.0f;

    for (int k0 = 0; k0 < K; k0 += 16) {
        const int rem = K - k0;
#pragma unroll
        for (int l = 0; l < 2; ++l) {
            int s = tid + l * 256;
            int r = s >> 2, kq = (s & 3) * 4;
            int gr = row0 + r;
            float v0 = 0, v1 = 0, v2 = 0, v3 = 0;
            if (gr < rows) {
                const float* xp = X + (long)gr * ldx + k0 + kq;
                if (xv && rem >= 16) {
                    float4 t4 = *(const float4*)xp;
                    v0 = t4.x; v1 = t4.y; v2 = t4.z; v3 = t4.w;
                } else {
                    if (kq + 0 < rem) v0 = xp[0];
                    if (kq + 1 < rem) v1 = xp[1];
                    if (kq + 2 < rem) v2 = xp[2];
                    if (kq + 3 < rem) v3 = xp[3];
                }
            }
            Xs[kq + 0][r] = v0; Xs[kq + 1][r] = v1;
            Xs[kq + 2][r] = v2; Xs[kq + 3][r] = v3;
        }
#pragma unroll
        for (int l = 0; l < 2; ++l) {
            int s = tid + l * 256;
            int r = s >> 2, kq = (s & 3) * 4;
            int gc = col0 + r;
            float v0 = 0, v1 = 0, v2 = 0, v3 = 0;
            if (gc < N) {
                const float* wp = W + (long)gc * ldw + k0 + kq;
                if (wv && rem >= 16) {
                    float4 t4 = *(const float4*)wp;
                    v0 = t4.x; v1 = t4.y; v2 = t4.z; v3 = t4.w;
                } else {
                    if (kq + 0 < rem) v0 = wp[0];
                    if (kq + 1 < rem) v1 = wp[1];
                    if (kq + 2 < rem) v2 = wp[2];
                    if (kq + 3 < rem) v3 = wp[3];
                }
            }
            Ws[kq + 0][r] = v0; Ws[kq + 1][r] = v1;
            Ws[kq + 2][r] = v2; Ws[kq + 3][r] = v3;
        }
        __syncthreads();
#pragma unroll
        for (int kk = 0; kk < 16; ++kk) {
            float4 xa = *(const float4*)&Xs[kk][tm];
            float4 xb = *(const float4*)&Xs[kk][tm + 4];
            float4 wa = *(const float4*)&Ws[kk][tn];
            float4 wb = *(const float4*)&Ws[kk][tn + 4];
            float xr[8] = {xa.x, xa.y, xa.z, xa.w, xb.x, xb.y, xb.z, xb.w};
            float wr[8] = {wa.x, wa.y, wa.z, wa.w, wb.x, wb.y, wb.z, wb.w};
#pragma unroll
            for (int i = 0; i < 8; ++i)
#pragma unroll
                for (int j = 0; j < 8; ++j)
                    acc[i][j] += xr[i] * wr[j];
        }
        __syncthreads();
    }

#pragma unroll
    for (int i = 0; i < 8; ++i) {
        int gr = row0 + tm + i;
        if (gr >= rows) continue;
#pragma unroll
        for (int j = 0; j < 8; ++j) {
            int gc = col0 + tn + j;
            if (gc >= N) continue;
            float v = acc[i][j];
            if (BIAS)  v += Bias[gc];
            if (ACCUM) v += C[(long)gr * ldc + gc];
            if (RELU)  v = fmaxf(v, 0.0f);
            C[(long)gr * ldc + gc] = v;
        }
    }
}

// ---------------------------------------------------------------------------
// gemm_half: N=150 (one col-block per 128-row stripe -> in-place safe), K=300.
// 320 threads (16 row-thr x 20 col-thr), 8x8 microtile, BN=160 padded.
// C[r*ldc + 0:150) = X[r, ldx] @ Wrow(n)=W[n*ldw..]  (n = 0..149)
// In-place safe when C==X-region: block reads only its own 128 rows (all K)
// during the k-loop and epilogue-writes only those rows after the final sync.
// ---------------------------------------------------------------------------
__global__ __launch_bounds__(320)
void gemm_half(const float* __restrict__ X, int ldx, const float* __restrict__ W, int ldw,
               float* __restrict__ C, int ldc, int rows, int K)
{
    __shared__ float Xs[16][132];
    __shared__ float Ws[16][164];
    const int row0 = blockIdx.x * 128;
    const int tid  = threadIdx.x;
    const int rt   = tid / 20;
    const int ct   = tid - rt * 20;
    const int tm   = rt * 8;
    const int tn   = ct * 8;

    float acc[8][8];
#pragma unroll
    for (int i = 0; i < 8; ++i)
#pragma unroll
        for (int j = 0; j < 8; ++j) acc[i][j] = 0.0f;

    for (int k0 = 0; k0 < K; k0 += 16) {
        const int rem = K - k0;
        for (int s = tid; s < 512; s += 320) {
            int r = s >> 2, kq = (s & 3) * 4;
            int gr = row0 + r;
            float v0 = 0, v1 = 0, v2 = 0, v3 = 0;
            if (gr < rows) {
                const float* xp = X + (long)gr * ldx + k0 + kq;
                if (rem >= 16) {
                    float4 t4 = *(const float4*)xp;
                    v0 = t4.x; v1 = t4.y; v2 = t4.z; v3 = t4.w;
                } else {
                    if (kq + 0 < rem) v0 = xp[0];
                    if (kq + 1 < rem) v1 = xp[1];
                    if (kq + 2 < rem) v2 = xp[2];
                    if (kq + 3 < rem) v3 = xp[3];
                }
            }
            Xs[kq + 0][r] = v0; Xs[kq + 1][r] = v1;
            Xs[kq + 2][r] = v2; Xs[kq + 3][r] = v3;
        }
        for (int s = tid; s < 640; s += 320) {
            int r = s >> 2, kq = (s & 3) * 4;
            float v0 = 0, v1 = 0, v2 = 0, v3 = 0;
            if (r < 150) {
                const float* wp = W + (long)r * ldw + k0 + kq;
                if (rem >= 16) {
                    float4 t4 = *(const float4*)wp;
                    v0 = t4.x; v1 = t4.y; v2 = t4.z; v3 = t4.w;
                } else {
                    if (kq + 0 < rem) v0 = wp[0];
                    if (kq + 1 < rem) v1 = wp[1];
                    if (kq + 2 < rem) v2 = wp[2];
                    if (kq + 3 < rem) v3 = wp[3];
                }
            }
            Ws[kq + 0][r] = v0; Ws[kq + 1][r] = v1;
            Ws[kq + 2][r] = v2; Ws[kq + 3][r] = v3;
        }
        __syncthreads();
#pragma unroll
        for (int kk = 0; kk < 16; ++kk) {
            float4 xa = *(const float4*)&Xs[kk][tm];
            float4 xb = *(const float4*)&Xs[kk][tm + 4];
            float4 wa = *(const float4*)&Ws[kk][tn];
            float4 wb = *(const float4*)&Ws[kk][tn + 4];
            float xr[8] = {xa.x, xa.y, xa.z, xa.w, xb.x, xb.y, xb.z, xb.w};
            float wr[8] = {wa.x, wa.y, wa.z, wa.w, wb.x, wb.y, wb.z, wb.w};
#pragma unroll
            for (int i = 0; i < 8; ++i)
#pragma unroll
                for (int j = 0; j < 8; ++j)
                    acc[i][j] += xr[i] * wr[j];
        }
        __syncthreads();
    }

#pragma unroll
    for (int i = 0; i < 8; ++i) {
        int gr = row0 + tm + i;
        if (gr >= rows) continue;
#pragma unroll
        for (int j = 0; j < 8; ++j) {
            int cn = tn + j;
            if (cn >= 150) continue;
            C[(long)gr * ldc + cn] = acc[i][j];
        }
    }
}

// ---------------------------------------------------------------------------
// bond_up: same geometry as gemm_half, K=147, with gather epilogue:
//  P[b, c0+cn] = relu( relu(FB[b]@WiB[c0+cn]) + Th[b2a[b],cn] - Vsrc[b2revb[b]*vstride+cn] )
// ---------------------------------------------------------------------------
__global__ __launch_bounds__(320)
void bond_up(const float* __restrict__ FB, const float* __restrict__ WiB,
             const float* __restrict__ Th, const float* __restrict__ Vsrc, int vstride,
             const int* __restrict__ b2a, const int* __restrict__ b2revb,
             float* __restrict__ P, int c0, int rows)
{
    __shared__ float Xs[16][132];
    __shared__ float Ws[16][164];
    __shared__ int ra[128], rb[128];
    const int row0 = blockIdx.x * 128;
    const int tid  = threadIdx.x;
    const int rt   = tid / 20;
    const int ct   = tid - rt * 20;
    const int tm   = rt * 8;
    const int tn   = ct * 8;

    if (tid < 128) {
        int gr = row0 + tid;
        ra[tid] = (gr < rows) ? b2a[gr] : 0;
    } else if (tid < 256) {
        int m = tid - 128;
        int gr = row0 + m;
        rb[m] = (gr < rows) ? b2revb[gr] : 0;
    }

    float acc[8][8];
#pragma unroll
    for (int i = 0; i < 8; ++i)
#pragma unroll
        for (int j = 0; j < 8; ++j) acc[i][j] = 0.0f;

    for (int k0 = 0; k0 < BFD; k0 += 16) {
        const int rem = BFD - k0;
        for (int s = tid; s < 512; s += 320) {
            int r = s >> 2, kq = (s & 3) * 4;
            int gr = row0 + r;
            float v0 = 0, v1 = 0, v2 = 0, v3 = 0;
            if (gr < rows) {
                const float* xp = FB + (long)gr * BFD + k0 + kq;
                if (kq + 0 < rem) v0 = xp[0];
                if (kq + 1 < rem) v1 = xp[1];
                if (kq + 2 < rem) v2 = xp[2];
                if (kq + 3 < rem) v3 = xp[3];
            }
            Xs[kq + 0][r] = v0; Xs[kq + 1][r] = v1;
            Xs[kq + 2][r] = v2; Xs[kq + 3][r] = v3;
        }
        for (int s = tid; s < 640; s += 320) {
            int r = s >> 2, kq = (s & 3) * 4;
            float v0 = 0, v1 = 0, v2 = 0, v3 = 0;
            if (r < 150) {
                const float* wp = WiB + (long)(c0 + r) * BFD + k0 + kq;
                if (kq + 0 < rem) v0 = wp[0];
                if (kq + 1 < rem) v1 = wp[1];
                if (kq + 2 < rem) v2 = wp[2];
                if (kq + 3 < rem) v3 = wp[3];
            }
            Ws[kq + 0][r] = v0; Ws[kq + 1][r] = v1;
            Ws[kq + 2][r] = v2; Ws[kq + 3][r] = v3;
        }
        __syncthreads();
#pragma unroll
        for (int kk = 0; kk < 16; ++kk) {
            float4 xa = *(const float4*)&Xs[kk][tm];
            float4 xb = *(const float4*)&Xs[kk][tm + 4];
            float4 wa = *(const float4*)&Ws[kk][tn];
            float4 wb = *(const float4*)&Ws[kk][tn + 4];
            float xr[8] = {xa.x, xa.y, xa.z, xa.w, xb.x, xb.y, xb.z, xb.w};
            float wr[8] = {wa.x, wa.y, wa.z, wa.w, wb.x, wb.y, wb.z, wb.w};
#pragma unroll
            for (int i = 0; i < 8; ++i)
#pragma unroll
                for (int j = 0; j < 8; ++j)
                    acc[i][j] += xr[i] * wr[j];
        }
        __syncthreads();
    }

#pragma unroll
    for (int i = 0; i < 8; ++i) {
        int gr = row0 + tm + i;
        if (gr >= rows) continue;
        int a  = ra[tm + i];
        int rv = rb[tm + i];
#pragma unroll
        for (int j = 0; j < 8; ++j) {
            int cn = tn + j;
            if (cn >= 150) continue;
            float ib = fmaxf(acc[i][j], 0.0f);
            float v  = ib + Th[(long)a * 150 + cn] - Vsrc[(long)rv * vstride + cn];
            P[(long)gr * 300 + c0 + cn] = fmaxf(v, 0.0f);
        }
    }
}

// transpose: in[N][K] -> out[K][N]
__global__ void transpose_kernel(const float* __restrict__ in, float* __restrict__ out,
                                 int N, int K)
{
    long idx = (long)blockIdx.x * blockDim.x + threadIdx.x;
    if (idx >= (long)N * K) return;
    int k = (int)(idx / N), n = (int)(idx - (long)k * N);
    out[idx] = in[(long)n * K + k];
}

template<bool ADD>
__global__ void aggregate(const float* __restrict__ mb, const int* __restrict__ a2b,
                          float* __restrict__ dst)
{
    long idx = (long)blockIdx.x * blockDim.x + threadIdx.x;
    if (idx >= (long)AA * HH) return;
    int a = (int)(idx / HH);
    int h = (int)(idx - (long)a * HH);
    const int* nb = a2b + (long)a * NBB;
    float s = 0.0f, mx = -INFINITY;
#pragma unroll
    for (int i = 0; i < NBB; ++i) {
        float v = mb[(long)nb[i] * HH + h];
        s += v;
        mx = fmaxf(mx, v);
    }
    float r = s * mx;
    if (ADD) r += dst[idx];
    dst[idx] = r;
}

__global__ void msgx_kernel(const float* __restrict__ node, const float* __restrict__ gbias,
                            float* __restrict__ msgx)
{
    long idx = (long)blockIdx.x * blockDim.x + threadIdx.x;
    if (idx >= (long)MLR * HH) return;
    int h = (int)(idx % HH);
    msgx[idx] = fmaxf(node[idx + HH] + gbias[h], 0.0f);
}

__global__ void h0_kernel(const float* __restrict__ node, float* __restrict__ hf)
{
    int idx = blockIdx.x * blockDim.x + threadIdx.x;
    if (idx >= MMOL * HH) return;
    int m = idx / HH;
    int h = idx - m * HH;
    long base = (long)(1 + m * LATM) * HH + h;
    float mx = -INFINITY;
    for (int t = 0; t < LATM; ++t) mx = fmaxf(mx, node[base + (long)t * HH]);
    hf[idx] = mx;
}

// ---------------------------------------------------------------------------
// GRU scan (gi interleaved [ML,1800]; row stride 1800). 256 blocks, 2 mols
// each, XCD-pinned dirs. gout written in-place into gi[t][0:300].
// ---------------------------------------------------------------------------
#define GSTR 1800
__global__ __launch_bounds__(1024)
void gru_scan3(const float* __restrict__ WhhT_f, const float* __restrict__ bhh_f,
               const float* __restrict__ WhhT_b, const float* __restrict__ bhh_b,
               const float* __restrict__ h0, float* __restrict__ gi_f,
               float* __restrict__ gi_b)
{
    const int bid  = blockIdx.x;
    const int xcd  = bid & 7;
    const int dir  = (xcd >= 4) ? 1 : 0;
    const int rank = (bid >> 3) * 4 + (xcd & 3);   // 0..127, bijective per dir
    const int m0   = rank * 2;
    const float* WhhT = dir ? WhhT_b : WhhT_f;
    const float* bhh  = dir ? bhh_b  : bhh_f;
    float*       gi   = dir ? gi_b   : gi_f;
    const int tid = threadIdx.x;

    __shared__ float hs[2][304];
    __shared__ float ghs[2][H3];

    float bb = (tid < H3) ? bhh[tid] : 0.0f;

    for (int i = tid; i < 150; i += 1024) {
        int mm = i / 75, q = (i - mm * 75) * 4;
        *(float4*)&hs[mm][q] = *(const float4*)&h0[(long)(m0 + mm) * HH + q];
    }
    __syncthreads();

    for (int s = 0; s < LATM; ++s) {
        const int t = dir ? (LATM - 1 - s) : s;

        if (tid < H3) {
            float a0 = 0.0f, a1 = 0.0f;
            const float* wh = WhhT + tid;
#pragma unroll 4
            for (int k0 = 0; k0 < HH; k0 += 4) {
                float w0 = wh[(long)(k0 + 0) * H3];
                float w1 = wh[(long)(k0 + 1) * H3];
                float w2 = wh[(long)(k0 + 2) * H3];
                float w3 = wh[(long)(k0 + 3) * H3];
                float4 h0v = *(const float4*)&hs[0][k0];
                float4 h1v = *(const float4*)&hs[1][k0];
                a0 += h0v.x * w0 + h0v.y * w1 + h0v.z * w2 + h0v.w * w3;
                a1 += h1v.x * w0 + h1v.y * w1 + h1v.z * w2 + h1v.w * w3;
            }
            ghs[0][tid] = a0 + bb;
            ghs[1][tid] = a1 + bb;
        }
        __syncthreads();

        if (tid < 2 * HH) {
            int mm = tid / HH, hh = tid - mm * HH;
            long row = (long)(m0 + mm) * LATM + t;
            float* g = gi + row * GSTR;
            float ir = g[hh], iz = g[HH + hh], inn = g[2 * HH + hh];
            float r  = sigm(ir + ghs[mm][hh]);
            float z  = sigm(iz + ghs[mm][HH + hh]);
            float nn = tanhf(inn + r * ghs[mm][2 * HH + hh]);
            float hn = (1.0f - z) * nn + z * hs[mm][hh];
            hs[mm][hh] = hn;
            g[hh] = hn;
        }
        __syncthreads();
    }
}

__global__ void mean_kernel(const float* __restrict__ ah, float* __restrict__ out)
{
    int idx = blockIdx.x * blockDim.x + threadIdx.x;
    if (idx >= MMOL * HH) return;
    int m = idx / HH;
    int j = idx - m * HH;
    long base = (long)m * LATM * HH + j;
    float s = 0.0f;
    for (int t = 0; t < LATM; ++t) s += ah[base + (long)t * HH];
    out[idx] = s * (1.0f / LATM);
}

// ---------------------------------------------------------------------------
static inline int cdiv(long a, long b) { return (int)((a + b - 1) / b); }

extern "C" void kernel_launch(void* const* d_in, const int* in_sizes, int n_in,
                              void* d_out, int out_size, void* d_ws, size_t ws_size,
                              hipStream_t stream)
{
    const float* f_atoms  = (const float*)d_in[0];
    const float* f_bonds  = (const float*)d_in[1];
    const int*   a2b      = (const int*)d_in[2];
    const int*   b2a      = (const int*)d_in[3];
    const int*   b2revb   = (const int*)d_in[4];
    const float* W_i_atom = (const float*)d_in[5];
    const float* W_i_bond = (const float*)d_in[6];
    const float* W_h0     = (const float*)d_in[7];
    const float* W_h1     = (const float*)d_in[8];
    const float* W_lr     = (const float*)d_in[9];
    const float* gru_bias = (const float*)d_in[10];
    const float* Wih_f    = (const float*)d_in[11];
    const float* Whh_f    = (const float*)d_in[12];
    const float* bih_f    = (const float*)d_in[13];
    const float* bhh_f    = (const float*)d_in[14];
    const float* Wih_b    = (const float*)d_in[15];
    const float* Whh_b    = (const float*)d_in[16];
    const float* bih_b    = (const float*)d_in[17];
    const float* bhh_b    = (const float*)d_in[18];
    const float* W_o      = (const float*)d_in[19];
    const float* b_o      = (const float*)d_in[20];
    float* out = (float*)d_out;

    // fp32 arena (total 295,530,016 <= proven ws floor).
    //   Depth: P@0 [B,300], S@157287600 [B,150], MA@235931408 [A,300],
    //          TH@275254208 [A,150] (T halves)
    //   Scan:  GI@0 [ML,1800] (ends 235,929,600); msgx/AH in MA;
    //          H0/WhhT_f/WhhT_b/Wcat/bcat in TH (T dead by then)
    const size_t NEED = 295530016;
    if (ws_size < NEED) return;

    char* b = (char*)d_ws;
    float* P   = (float*)b;
    float* S   = (float*)(b + 157287600);
    float* MA  = (float*)(b + 235931408);
    float* TH  = (float*)(b + 275254208);

    float* Pia  = P + (size_t)AA * HH;        // ia_rc [A,300]
    float* GI   = (float*)b;                  // [ML,1800]
    float* MSGX = MA;                         // [ML,300]
    float* AH   = MA;                         // atomhid [ML,300]
    float* H0   = TH;                         // [M,300]
    float* WhhT_f = TH + 76800;               // 270,000
    float* WhhT_b = TH + 346800;              // 270,000
    float* Wcat   = TH + 616800;              // 540,000 ([1800][300])
    float* bcat   = TH + 1156800;             // 1,800

    dim3 blk(256);
    const int gA = cdiv((long)AA * HH, 256);
    const int gBr = cdiv(BBND, 128);          // 1025 row-stripes
    const int gAr = cdiv(AA, 128);            // 257
    dim3 gmA (gAr,              cdiv(HH, 128));
    dim3 gmB (gBr,              cdiv(HH, 128));
    dim3 gmGI(cdiv(MLR, 128),   cdiv(1800, 128));
    dim3 gmO (cdiv(MLR, 128),   cdiv(HH, 128));

    // 1. ma = input_atom ; 2. mb0 = input_bond -> P
    gemm_w<true, false, false><<<gmA, blk, 0, stream>>>(
        f_atoms, AFD, W_i_atom, AFD, nullptr, MA, HH, AA, HH, AFD);
    gemm_w<true, false, false><<<gmB, blk, 0, stream>>>(
        f_bonds, BFD, W_i_bond, BFD, nullptr, P, HH, BBND, HH, BFD);

    // Depth loop (mb_d contiguous in P at entry; S, TH free)
    const float* Wh[2] = { W_h0, W_h1 };
    for (int d = 0; d < 2; ++d) {
        const float* W = Wh[d];
        aggregate<true><<<gA, blk, 0, stream>>>(P, a2b, MA);                  // ma += agg
        gemm_half<<<gBr, dim3(320), 0, stream>>>(                            // Vw_lo -> S
            P, HH, W, HH, S, 150, BBND, HH);
        gemm_half<<<gBr, dim3(320), 0, stream>>>(                            // Vw_hi -> P[:,0:150) in place
            P, HH, W + 150 * HH, HH, P, HH, BBND, HH);
        gemm_half<<<gAr, dim3(320), 0, stream>>>(                            // T_hi -> TH
            MA, HH, W + 150 * HH, HH, TH, 150, AA, HH);
        bond_up<<<gBr, dim3(320), 0, stream>>>(                              // mb' hi -> P[:,150:300)
            f_bonds, W_i_bond, TH, P, HH, b2a, b2revb, P, 150, BBND);
        gemm_half<<<gAr, dim3(320), 0, stream>>>(                            // T_lo -> TH
            MA, HH, W, HH, TH, 150, AA, HH);
        bond_up<<<gBr, dim3(320), 0, stream>>>(                              // mb' lo -> P[:,0:150)
            f_bonds, W_i_bond, TH, S, 150, b2a, b2revb, P, 0, BBND);
    }

    // Final aggregation -> S [A,300]
    aggregate<false><<<gA, blk, 0, stream>>>(P, a2b, S);

    // ia recomputed -> Pia ; node = [agg|ma|ia] @ W_lr^T -> P[0:A*300)
    gemm_w<true, false, false><<<gmA, blk, 0, stream>>>(
        f_atoms, AFD, W_i_atom, AFD, nullptr, Pia, HH, AA, HH, AFD);
    gemm_w<false, false, false><<<gmA, blk, 0, stream>>>(
        S,   HH, W_lr,          H3, nullptr, P, HH, AA, HH, HH);
    gemm_w<false, false, true><<<gmA, blk, 0, stream>>>(
        MA,  HH, W_lr + HH,     H3, nullptr, P, HH, AA, HH, HH);
    gemm_w<false, false, true><<<gmA, blk, 0, stream>>>(
        Pia, HH, W_lr + 2 * HH, H3, nullptr, P, HH, AA, HH, HH);

    // GRU prep: msgx -> MA, h0 -> TH, WhhT transposes, Wih/bih concat
    msgx_kernel<<<cdiv((long)MLR * HH, 256), blk, 0, stream>>>(P, gru_bias, MSGX);
    h0_kernel<<<cdiv(MMOL * HH, 256), blk, 0, stream>>>(P, H0);
    transpose_kernel<<<cdiv(270000, 256), blk, 0, stream>>>(Whh_f, WhhT_f, H3, HH);
    transpose_kernel<<<cdiv(270000, 256), blk, 0, stream>>>(Whh_b, WhhT_b, H3, HH);
    hipMemcpyAsync(Wcat,          Wih_f, 270000 * 4, hipMemcpyDeviceToDevice, stream);
    hipMemcpyAsync(Wcat + 270000, Wih_b, 270000 * 4, hipMemcpyDeviceToDevice, stream);
    hipMemcpyAsync(bcat,          bih_f, 900 * 4,    hipMemcpyDeviceToDevice, stream);
    hipMemcpyAsync(bcat + 900,    bih_b, 900 * 4,    hipMemcpyDeviceToDevice, stream);

    // gi (both dirs interleaved) = msgx @ Wcat^T + bcat -> GI [ML,1800]
    gemm_w<false, true, false><<<gmGI, blk, 0, stream>>>(
        MSGX, HH, Wcat, HH, bcat, GI, 1800, MLR, 1800, HH);

    // Fused bidirectional scan (gout in-place into gi[t][dir*900 + 0:300])
    gru_scan3<<<dim3(256), dim3(1024), 0, stream>>>(
        WhhT_f, bhh_f, WhhT_b, bhh_b, H0, GI, GI + 900);

    // atom_hiddens = relu(gout_f@Wo_lo^T + gout_b@Wo_hi^T + b_o) -> AH
    gemm_w<false, false, false><<<gmO, blk, 0, stream>>>(
        GI,       1800, W_o,      2 * HH, nullptr, AH, HH, MLR, HH, HH);
    gemm_w<true, true, true><<<gmO, blk, 0, stream>>>(
        GI + 900, 1800, W_o + HH, 2 * HH, b_o,     AH, HH, MLR, HH, HH);

    // mol_vecs -> out
    mean_kernel<<<cdiv(MMOL * HH, 256), blk, 0, stream>>>(AH, out);
}

// Round 9
// 7044.512 us; speedup vs baseline: 1.0311x; 1.0311x over previous
//
#include <hip/hip_runtime.h>
#include <math.h>

// Problem constants
#define HH   300
#define H3   900
#define MMOL 256
#define LATM 128
#define AA   32769        // 1 + 256*128
#define NBB  6
#define BBND 131073       // 1 + 4*256*128
#define AFD  133
#define BFD  147
#define MLR  (MMOL * LATM)   // 32768

static __device__ __forceinline__ float sigm(float x) { return 1.0f / (1.0f + expf(-x)); }

// ---------------------------------------------------------------------------
// Tiled fp32 GEMM, 128x64 tile, BK=16, 8x4 microtile, 256 threads.
// C[rows,N] = act( X[rows, ldx-strided] @ Wrow(n)=W[n*ldw ..]  (+Bias) (+=C) )
// ---------------------------------------------------------------------------
template<bool RELU, bool BIAS, bool ACCUM>
__global__ __launch_bounds__(256)
void gemm_big(const float* __restrict__ X, int ldx, const float* __restrict__ W, int ldw,
              const float* __restrict__ Bias, float* __restrict__ C,
              int rows, int N, int K)
{
    __shared__ float Xs[16][132];
    __shared__ float Ws[16][68];
    const int row0 = blockIdx.x * 128;
    const int col0 = blockIdx.y * 64;
    const int tid  = threadIdx.x;
    const int tm   = (tid >> 4) * 8;
    const int tn   = (tid & 15) * 4;
    const bool xv  = ((ldx & 3) == 0);
    const bool wv  = ((ldw & 3) == 0);

    float acc[8][4];
#pragma unroll
    for (int i = 0; i < 8; ++i)
#pragma unroll
        for (int j = 0; j < 4; ++j) acc[i][j] = 0.0f;

    for (int k0 = 0; k0 < K; k0 += 16) {
        const int rem = K - k0;
#pragma unroll
        for (int l = 0; l < 2; ++l) {
            int s = tid + l * 256;
            int r = s >> 2, kq = (s & 3) * 4;
            int gr = row0 + r;
            float v0 = 0, v1 = 0, v2 = 0, v3 = 0;
            if (gr < rows) {
                const float* xp = X + (long)gr * ldx + k0 + kq;
                if (xv && rem >= 16) {
                    float4 t4 = *(const float4*)xp;
                    v0 = t4.x; v1 = t4.y; v2 = t4.z; v3 = t4.w;
                } else {
                    if (kq + 0 < rem) v0 = xp[0];
                    if (kq + 1 < rem) v1 = xp[1];
                    if (kq + 2 < rem) v2 = xp[2];
                    if (kq + 3 < rem) v3 = xp[3];
                }
            }
            Xs[kq + 0][r] = v0; Xs[kq + 1][r] = v1;
            Xs[kq + 2][r] = v2; Xs[kq + 3][r] = v3;
        }
        {
            int r = tid >> 2, kq = (tid & 3) * 4;
            int gc = col0 + r;
            float v0 = 0, v1 = 0, v2 = 0, v3 = 0;
            if (gc < N) {
                const float* wp = W + (long)gc * ldw + k0 + kq;
                if (wv && rem >= 16) {
                    float4 t4 = *(const float4*)wp;
                    v0 = t4.x; v1 = t4.y; v2 = t4.z; v3 = t4.w;
                } else {
                    if (kq + 0 < rem) v0 = wp[0];
                    if (kq + 1 < rem) v1 = wp[1];
                    if (kq + 2 < rem) v2 = wp[2];
                    if (kq + 3 < rem) v3 = wp[3];
                }
            }
            Ws[kq + 0][r] = v0; Ws[kq + 1][r] = v1;
            Ws[kq + 2][r] = v2; Ws[kq + 3][r] = v3;
        }
        __syncthreads();
#pragma unroll
        for (int kk = 0; kk < 16; ++kk) {
            float4 xa = *(const float4*)&Xs[kk][tm];
            float4 xb = *(const float4*)&Xs[kk][tm + 4];
            float4 wq = *(const float4*)&Ws[kk][tn];
            float xr[8] = {xa.x, xa.y, xa.z, xa.w, xb.x, xb.y, xb.z, xb.w};
            float wr[4] = {wq.x, wq.y, wq.z, wq.w};
#pragma unroll
            for (int i = 0; i < 8; ++i)
#pragma unroll
                for (int j = 0; j < 4; ++j)
                    acc[i][j] += xr[i] * wr[j];
        }
        __syncthreads();
    }

#pragma unroll
    for (int i = 0; i < 8; ++i) {
        int gr = row0 + tm + i;
        if (gr >= rows) continue;
#pragma unroll
        for (int j = 0; j < 4; ++j) {
            int gc = col0 + tn + j;
            if (gc >= N) continue;
            float v = acc[i][j];
            if (BIAS)  v += Bias[gc];
            if (ACCUM) v += C[(long)gr * N + gc];
            if (RELU)  v = fmaxf(v, 0.0f);
            C[(long)gr * N + gc] = v;
        }
    }
}

// transpose: in[N][K] -> out[K][N]
__global__ void transpose_kernel(const float* __restrict__ in, float* __restrict__ out,
                                 int N, int K)
{
    long idx = (long)blockIdx.x * blockDim.x + threadIdx.x;
    if (idx >= (long)N * K) return;
    int k = (int)(idx / N), n = (int)(idx - (long)k * N);
    out[idx] = in[(long)n * K + k];
}

// ---------------------------------------------------------------------------
// In-place: P[r, 0:150) = (P[r, 0:300) @ W^T)[:, 150:300) via transposed WT.
// ---------------------------------------------------------------------------
__global__ __launch_bounds__(256)
void vw_hi_inplace(float* __restrict__ P, const float* __restrict__ WT, int rows)
{
    __shared__ float Xs[16][304];
    const int r0  = blockIdx.x * 16;
    const int tid = threadIdx.x;
    for (int i = tid; i < 16 * 300; i += 256) {
        int r = i / 300, c = i - r * 300;
        int gr = r0 + r;
        Xs[r][c] = (gr < rows) ? P[(long)gr * 300 + c] : 0.0f;
    }
    __syncthreads();

    const int r  = tid >> 4;
    const int cg = tid & 15;
    float acc[10];
#pragma unroll
    for (int u = 0; u < 10; ++u) acc[u] = 0.0f;

    for (int k = 0; k < 300; ++k) {
        float xv = Xs[r][k];
        const float* wt = WT + (long)k * 300 + 150 + cg;
#pragma unroll
        for (int u = 0; u < 10; ++u) {
            int j = cg + 16 * u;
            if (j < 150) acc[u] += xv * wt[16 * u];
        }
    }
    int gr = r0 + r;
    if (gr < rows) {
#pragma unroll
        for (int u = 0; u < 10; ++u) {
            int j = cg + 16 * u;
            if (j < 150) P[(long)gr * 300 + j] = acc[u];
        }
    }
}

// ---------------------------------------------------------------------------
// Half-column bond update (128x64 tiles, K=147 recomputed input_bond)
// ---------------------------------------------------------------------------
__global__ __launch_bounds__(256)
void bond_half(const float* __restrict__ FB, const float* __restrict__ WiB,
               const float* __restrict__ Th, const float* __restrict__ Vsrc, int vstride,
               const int* __restrict__ b2a, const int* __restrict__ b2revb,
               float* __restrict__ P, int c0, int rows)
{
    __shared__ float Xs[16][132];
    __shared__ float Ws[16][68];
    __shared__ int ra[128], rb[128];
    const int row0 = blockIdx.x * 128;
    const int col0 = blockIdx.y * 64;
    const int tid  = threadIdx.x;

    if (tid < 128) {
        int gr = row0 + tid;
        ra[tid] = (gr < rows) ? b2a[gr] : 0;
    } else {
        int m = tid - 128;
        int gr = row0 + m;
        rb[m] = (gr < rows) ? b2revb[gr] : 0;
    }

    const int tm = (tid >> 4) * 8;
    const int tn = (tid & 15) * 4;
    float acc[8][4];
#pragma unroll
    for (int i = 0; i < 8; ++i)
#pragma unroll
        for (int j = 0; j < 4; ++j) acc[i][j] = 0.0f;

    for (int k0 = 0; k0 < BFD; k0 += 16) {
        const int rem = BFD - k0;
#pragma unroll
        for (int l = 0; l < 2; ++l) {
            int s = tid + l * 256;
            int r = s >> 2, kq = (s & 3) * 4;
            int gr = row0 + r;
            float v0 = 0, v1 = 0, v2 = 0, v3 = 0;
            if (gr < rows) {
                const float* xp = FB + (long)gr * BFD + k0 + kq;
                if (kq + 0 < rem) v0 = xp[0];
                if (kq + 1 < rem) v1 = xp[1];
                if (kq + 2 < rem) v2 = xp[2];
                if (kq + 3 < rem) v3 = xp[3];
            }
            Xs[kq + 0][r] = v0; Xs[kq + 1][r] = v1;
            Xs[kq + 2][r] = v2; Xs[kq + 3][r] = v3;
        }
        {
            int r = tid >> 2, kq = (tid & 3) * 4;
            int gc = col0 + r;
            float v0 = 0, v1 = 0, v2 = 0, v3 = 0;
            if (gc < 150) {
                const float* wp = WiB + (long)(c0 + gc) * BFD + k0 + kq;
                if (kq + 0 < rem) v0 = wp[0];
                if (kq + 1 < rem) v1 = wp[1];
                if (kq + 2 < rem) v2 = wp[2];
                if (kq + 3 < rem) v3 = wp[3];
            }
            Ws[kq + 0][r] = v0; Ws[kq + 1][r] = v1;
            Ws[kq + 2][r] = v2; Ws[kq + 3][r] = v3;
        }
        __syncthreads();
#pragma unroll
        for (int kk = 0; kk < 16; ++kk) {
            float4 xa = *(const float4*)&Xs[kk][tm];
            float4 xb = *(const float4*)&Xs[kk][tm + 4];
            float4 wq = *(const float4*)&Ws[kk][tn];
            float xr[8] = {xa.x, xa.y, xa.z, xa.w, xb.x, xb.y, xb.z, xb.w};
            float wr[4] = {wq.x, wq.y, wq.z, wq.w};
#pragma unroll
            for (int i = 0; i < 8; ++i)
#pragma unroll
                for (int j = 0; j < 4; ++j)
                    acc[i][j] += xr[i] * wr[j];
        }
        __syncthreads();
    }

#pragma unroll
    for (int i = 0; i < 8; ++i) {
        int gr = row0 + tm + i;
        if (gr >= rows) continue;
        int a  = ra[tm + i];
        int rv = rb[tm + i];
#pragma unroll
        for (int j = 0; j < 4; ++j) {
            int cn = col0 + tn + j;
            if (cn >= 150) continue;
            float ib = fmaxf(acc[i][j], 0.0f);
            float v  = ib + Th[(long)a * 150 + cn] - Vsrc[(long)rv * vstride + cn];
            P[(long)gr * 300 + c0 + cn] = fmaxf(v, 0.0f);
        }
    }
}

template<bool ADD>
__global__ void aggregate(const float* __restrict__ mb, const int* __restrict__ a2b,
                          float* __restrict__ dst)
{
    long idx = (long)blockIdx.x * blockDim.x + threadIdx.x;
    if (idx >= (long)AA * HH) return;
    int a = (int)(idx / HH);
    int h = (int)(idx - (long)a * HH);
    const int* nb = a2b + (long)a * NBB;
    float s = 0.0f, mx = -INFINITY;
#pragma unroll
    for (int i = 0; i < NBB; ++i) {
        float v = mb[(long)nb[i] * HH + h];
        s += v;
        mx = fmaxf(mx, v);
    }
    float r = s * mx;
    if (ADD) r += dst[idx];
    dst[idx] = r;
}

__global__ void msgx_kernel(const float* __restrict__ node, const float* __restrict__ gbias,
                            float* __restrict__ msgx)
{
    long idx = (long)blockIdx.x * blockDim.x + threadIdx.x;
    if (idx >= (long)MLR * HH) return;
    int h = (int)(idx % HH);
    msgx[idx] = fmaxf(node[idx + HH] + gbias[h], 0.0f);
}

__global__ void h0_kernel(const float* __restrict__ node, float* __restrict__ hf)
{
    int idx = blockIdx.x * blockDim.x + threadIdx.x;
    if (idx >= MMOL * HH) return;
    int m = idx / HH;
    int h = idx - m * HH;
    long base = (long)(1 + m * LATM) * HH + h;
    float mx = -INFINITY;
    for (int t = 0; t < LATM; ++t) mx = fmaxf(mx, node[base + (long)t * HH]);
    hf[idx] = mx;
}

// ---------------------------------------------------------------------------
// GRU scan v4: gi precomputed; 128 blocks, 4 mols/block, XCD-pinned dirs
// (dir 0 -> XCDs 0-3, dir 1 -> XCDs 4-7). Halved per-XCD L2 weight traffic
// vs G=2 (16 blocks/XCD x 1.08 MB x 128 steps = 2.2 GB -> ~0.5 ms floor).
// Per-gate accumulation order identical to v3 -> bit-identical results.
// gout written in-place into gi[t][0:300] after last read of that slot.
// ---------------------------------------------------------------------------
__global__ __launch_bounds__(1024)
void gru_scan4(const float* __restrict__ WhhT_f, const float* __restrict__ bhh_f,
               const float* __restrict__ WhhT_b, const float* __restrict__ bhh_b,
               const float* __restrict__ h0, float* __restrict__ gi_f,
               float* __restrict__ gi_b)
{
    const int bid  = blockIdx.x;                   // 0..127
    const int xcd  = bid & 7;
    const int dir  = (xcd >= 4) ? 1 : 0;
    const int rank = (bid >> 3) * 4 + (xcd & 3);   // 0..63, bijective per dir
    const int m0   = rank * 4;
    const float* WhhT = dir ? WhhT_b : WhhT_f;
    const float* bhh  = dir ? bhh_b  : bhh_f;
    float*       gi   = dir ? gi_b   : gi_f;
    const int tid = threadIdx.x;

    __shared__ float hs[4][304];
    __shared__ float ghs[4][H3];

    float bb = (tid < H3) ? bhh[tid] : 0.0f;

    for (int i = tid; i < 300; i += 1024) {        // 4 mols x 75 float4
        int mm = i / 75, q = (i - mm * 75) * 4;
        *(float4*)&hs[mm][q] = *(const float4*)&h0[(long)(m0 + mm) * HH + q];
    }
    __syncthreads();

    for (int s = 0; s < LATM; ++s) {
        const int t = dir ? (LATM - 1 - s) : s;

        // phase 1: gh for all 900 gate units x 4 mols
        if (tid < H3) {
            float a0 = 0.0f, a1 = 0.0f, a2 = 0.0f, a3 = 0.0f;
            const float* wh = WhhT + tid;
#pragma unroll 2
            for (int k0 = 0; k0 < HH; k0 += 4) {
                float w0 = wh[(long)(k0 + 0) * H3];
                float w1 = wh[(long)(k0 + 1) * H3];
                float w2 = wh[(long)(k0 + 2) * H3];
                float w3 = wh[(long)(k0 + 3) * H3];
                float4 h0v = *(const float4*)&hs[0][k0];
                float4 h1v = *(const float4*)&hs[1][k0];
                float4 h2v = *(const float4*)&hs[2][k0];
                float4 h3v = *(const float4*)&hs[3][k0];
                a0 += h0v.x * w0 + h0v.y * w1 + h0v.z * w2 + h0v.w * w3;
                a1 += h1v.x * w0 + h1v.y * w1 + h1v.z * w2 + h1v.w * w3;
                a2 += h2v.x * w0 + h2v.y * w1 + h2v.z * w2 + h2v.w * w3;
                a3 += h3v.x * w0 + h3v.y * w1 + h3v.z * w2 + h3v.w * w3;
            }
            ghs[0][tid] = a0 + bb;
            ghs[1][tid] = a1 + bb;
            ghs[2][tid] = a2 + bb;
            ghs[3][tid] = a3 + bb;
        }
        __syncthreads();

        // phase 2: gates, state update, in-place gout (4*300 = 1200 elems)
        for (int i = tid; i < 4 * HH; i += 1024) {
            int mm = i / HH, hh = i - mm * HH;
            long row = (long)(m0 + mm) * LATM + t;
            float* g = gi + row * H3;
            float ir = g[hh], iz = g[HH + hh], inn = g[2 * HH + hh];
            float r  = sigm(ir + ghs[mm][hh]);
            float z  = sigm(iz + ghs[mm][HH + hh]);
            float nn = tanhf(inn + r * ghs[mm][2 * HH + hh]);
            float hn = (1.0f - z) * nn + z * hs[mm][hh];
            hs[mm][hh] = hn;
            g[hh] = hn;
        }
        __syncthreads();
    }
}

__global__ void mean_kernel(const float* __restrict__ ah, float* __restrict__ out)
{
    int idx = blockIdx.x * blockDim.x + threadIdx.x;
    if (idx >= MMOL * HH) return;
    int m = idx / HH;
    int j = idx - m * HH;
    long base = (long)m * LATM * HH + j;
    float s = 0.0f;
    for (int t = 0; t < LATM; ++t) s += ah[base + (long)t * HH];
    out[idx] = s * (1.0f / LATM);
}

// ---------------------------------------------------------------------------
static inline int cdiv(long a, long b) { return (int)((a + b - 1) / b); }

extern "C" void kernel_launch(void* const* d_in, const int* in_sizes, int n_in,
                              void* d_out, int out_size, void* d_ws, size_t ws_size,
                              hipStream_t stream)
{
    const float* f_atoms  = (const float*)d_in[0];
    const float* f_bonds  = (const float*)d_in[1];
    const int*   a2b      = (const int*)d_in[2];
    const int*   b2a      = (const int*)d_in[3];
    const int*   b2revb   = (const int*)d_in[4];
    const float* W_i_atom = (const float*)d_in[5];
    const float* W_i_bond = (const float*)d_in[6];
    const float* W_h0     = (const float*)d_in[7];
    const float* W_h1     = (const float*)d_in[8];
    const float* W_lr     = (const float*)d_in[9];
    const float* gru_bias = (const float*)d_in[10];
    const float* Wih_f    = (const float*)d_in[11];
    const float* Whh_f    = (const float*)d_in[12];
    const float* bih_f    = (const float*)d_in[13];
    const float* bhh_f    = (const float*)d_in[14];
    const float* Wih_b    = (const float*)d_in[15];
    const float* Whh_b    = (const float*)d_in[16];
    const float* bih_b    = (const float*)d_in[17];
    const float* bhh_b    = (const float*)d_in[18];
    const float* W_o      = (const float*)d_in[19];
    const float* b_o      = (const float*)d_in[20];
    float* out = (float*)d_out;

    // fp32 arena (total 295,530,016 <= proven ws floor).
    // Depth-loop regions: P@0, S@157287600, MA@235931408, TH@275254208,
    // HFB@294915616. Scan overlays: gi_f@0, gi_b@117964800, msgx/AH in MA,
    // h0 + WhhT_f/b in TH, WT depth scratch @HFB.
    const size_t NEED = 295530016;
    if (ws_size < NEED) return;

    char* b = (char*)d_ws;
    float* P   = (float*)b;
    float* S   = (float*)(b + 157287600);
    float* MA  = (float*)(b + 235931408);
    float* TH  = (float*)(b + 275254208);
    float* HFB = (float*)(b + 294915616);

    float* Pia  = P + (size_t)AA * HH;        // ia_rc [A,300]
    float* WT   = HFB;                        // depth-loop 300x300 transpose
    float* giF  = (float*)b;                  // [ML,900]
    float* giB  = (float*)(b + 117964800);    // [ML,900]
    float* MSGX = MA;                         // [ML,300] (MA dead post-node)
    float* AH   = MA;                         // atomhid [ML,300]
    float* H0   = TH;                         // [M,300]
    float* WhhT_f = TH + 76800;               // 270,000 floats
    float* WhhT_b = TH + 346800;              // 270,000 floats

    dim3 blk(256);
    const int gA = cdiv((long)AA * HH, 256);
    dim3 gmA (cdiv(AA, 128),   cdiv(HH, 64));
    dim3 gmB3(cdiv(BBND, 128), cdiv(HH, 64));
    dim3 gmB1(cdiv(BBND, 128), cdiv(150, 64));
    dim3 gmT (cdiv(AA, 128),   cdiv(150, 64));
    dim3 gmG (cdiv(MLR, 128),  cdiv(H3, 64));
    dim3 gmO (cdiv(MLR, 128),  cdiv(HH, 64));

    // 1. ma = input_atom ; 2. mb0 = input_bond -> P
    gemm_big<true, false, false><<<gmA, blk, 0, stream>>>(
        f_atoms, AFD, W_i_atom, AFD, nullptr, MA, AA, HH, AFD);
    gemm_big<true, false, false><<<gmB3, blk, 0, stream>>>(
        f_bonds, BFD, W_i_bond, BFD, nullptr, P, BBND, HH, BFD);

    // Depth loop
    const float* Wh[2] = { W_h0, W_h1 };
    for (int d = 0; d < 2; ++d) {
        const float* W = Wh[d];
        aggregate<true><<<gA, blk, 0, stream>>>(P, a2b, MA);
        transpose_kernel<<<cdiv(90000, 256), blk, 0, stream>>>(W, WT, 300, 300);
        gemm_big<false, false, false><<<gmB1, blk, 0, stream>>>(
            P, HH, W, HH, nullptr, S, BBND, 150, HH);
        vw_hi_inplace<<<cdiv(BBND, 16), blk, 0, stream>>>(P, WT, BBND);
        gemm_big<false, false, false><<<gmT, blk, 0, stream>>>(
            MA, HH, W + 150 * HH, HH, nullptr, TH, AA, 150, HH);
        bond_half<<<gmB1, blk, 0, stream>>>(
            f_bonds, W_i_bond, TH, P, 300, b2a, b2revb, P, 150, BBND);
        gemm_big<false, false, false><<<gmT, blk, 0, stream>>>(
            MA, HH, W, HH, nullptr, TH, AA, 150, HH);
        bond_half<<<gmB1, blk, 0, stream>>>(
            f_bonds, W_i_bond, TH, S, 150, b2a, b2revb, P, 0, BBND);
    }

    // Final aggregation -> S
    aggregate<false><<<gA, blk, 0, stream>>>(P, a2b, S);

    // ia recomputed -> Pia ; node -> P[0:A*300)
    gemm_big<true, false, false><<<gmA, blk, 0, stream>>>(
        f_atoms, AFD, W_i_atom, AFD, nullptr, Pia, AA, HH, AFD);
    gemm_big<false, false, false><<<gmA, blk, 0, stream>>>(
        S,   HH, W_lr,          H3, nullptr, P, AA, HH, HH);
    gemm_big<false, false, true><<<gmA, blk, 0, stream>>>(
        MA,  HH, W_lr + HH,     H3, nullptr, P, AA, HH, HH);
    gemm_big<false, false, true><<<gmA, blk, 0, stream>>>(
        Pia, HH, W_lr + 2 * HH, H3, nullptr, P, AA, HH, HH);

    // GRU prep: msgx -> MA region, h0 -> TH, WhhT transposes -> TH
    msgx_kernel<<<cdiv((long)MLR * HH, 256), blk, 0, stream>>>(P, gru_bias, MSGX);
    h0_kernel<<<cdiv(MMOL * HH, 256), blk, 0, stream>>>(P, H0);
    transpose_kernel<<<cdiv(270000, 256), blk, 0, stream>>>(Whh_f, WhhT_f, H3, HH);
    transpose_kernel<<<cdiv(270000, 256), blk, 0, stream>>>(Whh_b, WhhT_b, H3, HH);

    // gi = msgx @ Wih^T + bih (both dirs; overwrites node/mb/agg — all dead)
    gemm_big<false, true, false><<<gmG, blk, 0, stream>>>(
        MSGX, HH, Wih_f, HH, bih_f, giF, MLR, H3, HH);
    gemm_big<false, true, false><<<gmG, blk, 0, stream>>>(
        MSGX, HH, Wih_b, HH, bih_b, giB, MLR, H3, HH);

    // Fused bidirectional scan (gout in-place into gi[t][0:300])
    gru_scan4<<<dim3(128), dim3(1024), 0, stream>>>(
        WhhT_f, bhh_f, WhhT_b, bhh_b, H0, giF, giB);

    // atom_hiddens = relu(gout_f@Wo_lo^T + gout_b@Wo_hi^T + b_o) -> AH
    gemm_big<false, false, false><<<gmO, blk, 0, stream>>>(
        giF, H3, W_o,      2 * HH, nullptr, AH, MLR, HH, HH);
    gemm_big<true, true, true><<<gmO, blk, 0, stream>>>(
        giB, H3, W_o + HH, 2 * HH, b_o,     AH, MLR, HH, HH);

    // mol_vecs -> out
    mean_kernel<<<cdiv(MMOL * HH, 256), blk, 0, stream>>>(AH, out);
}

// Round 10
// 5624.272 us; speedup vs baseline: 1.2915x; 1.2525x over previous
//
#include <hip/hip_runtime.h>
#include <math.h>

// Problem constants
#define HH   300
#define H3   900
#define MMOL 256
#define LATM 128
#define AA   32769        // 1 + 256*128
#define NBB  6
#define BBND 131073       // 1 + 4*256*128
#define AFD  133
#define BFD  147
#define MLR  (MMOL * LATM)   // 32768

static __device__ __forceinline__ float sigm(float x) { return 1.0f / (1.0f + expf(-x)); }

// ---------------------------------------------------------------------------
// Tiled fp32 GEMM, 128x64 tile, BK=16, 8x4 microtile, 256 threads.
// C[rows,N] = act( X[rows, ldx-strided] @ Wrow(n)=W[n*ldw ..]  (+Bias) (+=C) )
// ---------------------------------------------------------------------------
template<bool RELU, bool BIAS, bool ACCUM>
__global__ __launch_bounds__(256)
void gemm_big(const float* __restrict__ X, int ldx, const float* __restrict__ W, int ldw,
              const float* __restrict__ Bias, float* __restrict__ C,
              int rows, int N, int K)
{
    __shared__ float Xs[16][132];
    __shared__ float Ws[16][68];
    const int row0 = blockIdx.x * 128;
    const int col0 = blockIdx.y * 64;
    const int tid  = threadIdx.x;
    const int tm   = (tid >> 4) * 8;
    const int tn   = (tid & 15) * 4;
    const bool xv  = ((ldx & 3) == 0);
    const bool wv  = ((ldw & 3) == 0);

    float acc[8][4];
#pragma unroll
    for (int i = 0; i < 8; ++i)
#pragma unroll
        for (int j = 0; j < 4; ++j) acc[i][j] = 0.0f;

    for (int k0 = 0; k0 < K; k0 += 16) {
        const int rem = K - k0;
#pragma unroll
        for (int l = 0; l < 2; ++l) {
            int s = tid + l * 256;
            int r = s >> 2, kq = (s & 3) * 4;
            int gr = row0 + r;
            float v0 = 0, v1 = 0, v2 = 0, v3 = 0;
            if (gr < rows) {
                const float* xp = X + (long)gr * ldx + k0 + kq;
                if (xv && rem >= 16) {
                    float4 t4 = *(const float4*)xp;
                    v0 = t4.x; v1 = t4.y; v2 = t4.z; v3 = t4.w;
                } else {
                    if (kq + 0 < rem) v0 = xp[0];
                    if (kq + 1 < rem) v1 = xp[1];
                    if (kq + 2 < rem) v2 = xp[2];
                    if (kq + 3 < rem) v3 = xp[3];
                }
            }
            Xs[kq + 0][r] = v0; Xs[kq + 1][r] = v1;
            Xs[kq + 2][r] = v2; Xs[kq + 3][r] = v3;
        }
        {
            int r = tid >> 2, kq = (tid & 3) * 4;
            int gc = col0 + r;
            float v0 = 0, v1 = 0, v2 = 0, v3 = 0;
            if (gc < N) {
                const float* wp = W + (long)gc * ldw + k0 + kq;
                if (wv && rem >= 16) {
                    float4 t4 = *(const float4*)wp;
                    v0 = t4.x; v1 = t4.y; v2 = t4.z; v3 = t4.w;
                } else {
                    if (kq + 0 < rem) v0 = wp[0];
                    if (kq + 1 < rem) v1 = wp[1];
                    if (kq + 2 < rem) v2 = wp[2];
                    if (kq + 3 < rem) v3 = wp[3];
                }
            }
            Ws[kq + 0][r] = v0; Ws[kq + 1][r] = v1;
            Ws[kq + 2][r] = v2; Ws[kq + 3][r] = v3;
        }
        __syncthreads();
#pragma unroll
        for (int kk = 0; kk < 16; ++kk) {
            float4 xa = *(const float4*)&Xs[kk][tm];
            float4 xb = *(const float4*)&Xs[kk][tm + 4];
            float4 wq = *(const float4*)&Ws[kk][tn];
            float xr[8] = {xa.x, xa.y, xa.z, xa.w, xb.x, xb.y, xb.z, xb.w};
            float wr[4] = {wq.x, wq.y, wq.z, wq.w};
#pragma unroll
            for (int i = 0; i < 8; ++i)
#pragma unroll
                for (int j = 0; j < 4; ++j)
                    acc[i][j] += xr[i] * wr[j];
        }
        __syncthreads();
    }

#pragma unroll
    for (int i = 0; i < 8; ++i) {
        int gr = row0 + tm + i;
        if (gr >= rows) continue;
#pragma unroll
        for (int j = 0; j < 4; ++j) {
            int gc = col0 + tn + j;
            if (gc >= N) continue;
            float v = acc[i][j];
            if (BIAS)  v += Bias[gc];
            if (ACCUM) v += C[(long)gr * N + gc];
            if (RELU)  v = fmaxf(v, 0.0f);
            C[(long)gr * N + gc] = v;
        }
    }
}

// transpose: in[N][K] -> out[K][N]
__global__ void transpose_kernel(const float* __restrict__ in, float* __restrict__ out,
                                 int N, int K)
{
    long idx = (long)blockIdx.x * blockDim.x + threadIdx.x;
    if (idx >= (long)N * K) return;
    int k = (int)(idx / N), n = (int)(idx - (long)k * N);
    out[idx] = in[(long)n * K + k];
}

// ---------------------------------------------------------------------------
// vw_hi_gemm: in-place staged GEMM.
//   P[r, 0:150) = (P[r, 0:300) @ W^T)[:, 150:300)
// Block = 128-row stripe x ALL 150 cols (3 chunks of 64, 3rd partial).
// 256 threads, 8 rows x (3x4) cols per thread, BK=16.
// In-place safe: all global reads of P (staging, own rows only) complete
// before the final barrier; epilogue then writes only own rows/cols.
// Accumulation over k is sequential ascending -> bit-identical to the
// previous vw_hi_inplace.
// ---------------------------------------------------------------------------
__global__ __launch_bounds__(256)
void vw_hi_gemm(float* __restrict__ P, const float* __restrict__ W, int rows)
{
    __shared__ float Xs[16][132];
    __shared__ float Ws[16][192];
    const int row0 = blockIdx.x * 128;
    const int tid  = threadIdx.x;
    const int tm   = (tid >> 4) * 8;
    const int tn   = (tid & 15) * 4;

    float acc[8][12];
#pragma unroll
    for (int i = 0; i < 8; ++i)
#pragma unroll
        for (int j = 0; j < 12; ++j) acc[i][j] = 0.0f;

    for (int k0 = 0; k0 < 300; k0 += 16) {
        const int rem = 300 - k0;
#pragma unroll
        for (int l = 0; l < 2; ++l) {
            int s = tid + l * 256;
            int r = s >> 2, kq = (s & 3) * 4;
            int gr = row0 + r;
            float v0 = 0, v1 = 0, v2 = 0, v3 = 0;
            if (gr < rows) {
                const float* xp = P + (long)gr * 300 + k0 + kq;
                if (rem >= 16) {
                    float4 t4 = *(const float4*)xp;
                    v0 = t4.x; v1 = t4.y; v2 = t4.z; v3 = t4.w;
                } else {
                    if (kq + 0 < rem) v0 = xp[0];
                    if (kq + 1 < rem) v1 = xp[1];
                    if (kq + 2 < rem) v2 = xp[2];
                    if (kq + 3 < rem) v3 = xp[3];
                }
            }
            Xs[kq + 0][r] = v0; Xs[kq + 1][r] = v1;
            Xs[kq + 2][r] = v2; Xs[kq + 3][r] = v3;
        }
        // stage W rows 150..299 (output cols 0..149): 600 float4 slots
        for (int s = tid; s < 600; s += 256) {
            int r = s >> 2, kq = (s & 3) * 4;
            const float* wp = W + (long)(150 + r) * 300 + k0 + kq;
            float v0 = 0, v1 = 0, v2 = 0, v3 = 0;
            if (rem >= 16) {
                float4 t4 = *(const float4*)wp;
                v0 = t4.x; v1 = t4.y; v2 = t4.z; v3 = t4.w;
            } else {
                if (kq + 0 < rem) v0 = wp[0];
                if (kq + 1 < rem) v1 = wp[1];
                if (kq + 2 < rem) v2 = wp[2];
                if (kq + 3 < rem) v3 = wp[3];
            }
            Ws[kq + 0][r] = v0; Ws[kq + 1][r] = v1;
            Ws[kq + 2][r] = v2; Ws[kq + 3][r] = v3;
        }
        __syncthreads();
#pragma unroll
        for (int kk = 0; kk < 16; ++kk) {
            float4 xa = *(const float4*)&Xs[kk][tm];
            float4 xb = *(const float4*)&Xs[kk][tm + 4];
            float4 w0 = *(const float4*)&Ws[kk][tn];
            float4 w1 = *(const float4*)&Ws[kk][tn + 64];
            float4 w2 = *(const float4*)&Ws[kk][tn + 128];
            float xr[8] = {xa.x, xa.y, xa.z, xa.w, xb.x, xb.y, xb.z, xb.w};
            float wr[12] = {w0.x, w0.y, w0.z, w0.w, w1.x, w1.y, w1.z, w1.w,
                            w2.x, w2.y, w2.z, w2.w};
#pragma unroll
            for (int i = 0; i < 8; ++i)
#pragma unroll
                for (int j = 0; j < 12; ++j)
                    acc[i][j] += xr[i] * wr[j];
        }
        __syncthreads();
    }

#pragma unroll
    for (int i = 0; i < 8; ++i) {
        int gr = row0 + tm + i;
        if (gr >= rows) continue;
#pragma unroll
        for (int c = 0; c < 3; ++c)
#pragma unroll
            for (int j = 0; j < 4; ++j) {
                int cn = tn + c * 64 + j;
                if (cn < 150) P[(long)gr * 300 + cn] = acc[i][c * 4 + j];
            }
    }
}

// ---------------------------------------------------------------------------
// Half-column bond update (128x64 tiles, K=147 recomputed input_bond)
// ---------------------------------------------------------------------------
__global__ __launch_bounds__(256)
void bond_half(const float* __restrict__ FB, const float* __restrict__ WiB,
               const float* __restrict__ Th, const float* __restrict__ Vsrc, int vstride,
               const int* __restrict__ b2a, const int* __restrict__ b2revb,
               float* __restrict__ P, int c0, int rows)
{
    __shared__ float Xs[16][132];
    __shared__ float Ws[16][68];
    __shared__ int ra[128], rb[128];
    const int row0 = blockIdx.x * 128;
    const int col0 = blockIdx.y * 64;
    const int tid  = threadIdx.x;

    if (tid < 128) {
        int gr = row0 + tid;
        ra[tid] = (gr < rows) ? b2a[gr] : 0;
    } else {
        int m = tid - 128;
        int gr = row0 + m;
        rb[m] = (gr < rows) ? b2revb[gr] : 0;
    }

    const int tm = (tid >> 4) * 8;
    const int tn = (tid & 15) * 4;
    float acc[8][4];
#pragma unroll
    for (int i = 0; i < 8; ++i)
#pragma unroll
        for (int j = 0; j < 4; ++j) acc[i][j] = 0.0f;

    for (int k0 = 0; k0 < BFD; k0 += 16) {
        const int rem = BFD - k0;
#pragma unroll
        for (int l = 0; l < 2; ++l) {
            int s = tid + l * 256;
            int r = s >> 2, kq = (s & 3) * 4;
            int gr = row0 + r;
            float v0 = 0, v1 = 0, v2 = 0, v3 = 0;
            if (gr < rows) {
                const float* xp = FB + (long)gr * BFD + k0 + kq;
                if (kq + 0 < rem) v0 = xp[0];
                if (kq + 1 < rem) v1 = xp[1];
                if (kq + 2 < rem) v2 = xp[2];
                if (kq + 3 < rem) v3 = xp[3];
            }
            Xs[kq + 0][r] = v0; Xs[kq + 1][r] = v1;
            Xs[kq + 2][r] = v2; Xs[kq + 3][r] = v3;
        }
        {
            int r = tid >> 2, kq = (tid & 3) * 4;
            int gc = col0 + r;
            float v0 = 0, v1 = 0, v2 = 0, v3 = 0;
            if (gc < 150) {
                const float* wp = WiB + (long)(c0 + gc) * BFD + k0 + kq;
                if (kq + 0 < rem) v0 = wp[0];
                if (kq + 1 < rem) v1 = wp[1];
                if (kq + 2 < rem) v2 = wp[2];
                if (kq + 3 < rem) v3 = wp[3];
            }
            Ws[kq + 0][r] = v0; Ws[kq + 1][r] = v1;
            Ws[kq + 2][r] = v2; Ws[kq + 3][r] = v3;
        }
        __syncthreads();
#pragma unroll
        for (int kk = 0; kk < 16; ++kk) {
            float4 xa = *(const float4*)&Xs[kk][tm];
            float4 xb = *(const float4*)&Xs[kk][tm + 4];
            float4 wq = *(const float4*)&Ws[kk][tn];
            float xr[8] = {xa.x, xa.y, xa.z, xa.w, xb.x, xb.y, xb.z, xb.w};
            float wr[4] = {wq.x, wq.y, wq.z, wq.w};
#pragma unroll
            for (int i = 0; i < 8; ++i)
#pragma unroll
                for (int j = 0; j < 4; ++j)
                    acc[i][j] += xr[i] * wr[j];
        }
        __syncthreads();
    }

#pragma unroll
    for (int i = 0; i < 8; ++i) {
        int gr = row0 + tm + i;
        if (gr >= rows) continue;
        int a  = ra[tm + i];
        int rv = rb[tm + i];
#pragma unroll
        for (int j = 0; j < 4; ++j) {
            int cn = col0 + tn + j;
            if (cn >= 150) continue;
            float ib = fmaxf(acc[i][j], 0.0f);
            float v  = ib + Th[(long)a * 150 + cn] - Vsrc[(long)rv * vstride + cn];
            P[(long)gr * 300 + c0 + cn] = fmaxf(v, 0.0f);
        }
    }
}

template<bool ADD>
__global__ void aggregate(const float* __restrict__ mb, const int* __restrict__ a2b,
                          float* __restrict__ dst)
{
    long idx = (long)blockIdx.x * blockDim.x + threadIdx.x;
    if (idx >= (long)AA * HH) return;
    int a = (int)(idx / HH);
    int h = (int)(idx - (long)a * HH);
    const int* nb = a2b + (long)a * NBB;
    float s = 0.0f, mx = -INFINITY;
#pragma unroll
    for (int i = 0; i < NBB; ++i) {
        float v = mb[(long)nb[i] * HH + h];
        s += v;
        mx = fmaxf(mx, v);
    }
    float r = s * mx;
    if (ADD) r += dst[idx];
    dst[idx] = r;
}

__global__ void msgx_kernel(const float* __restrict__ node, const float* __restrict__ gbias,
                            float* __restrict__ msgx)
{
    long idx = (long)blockIdx.x * blockDim.x + threadIdx.x;
    if (idx >= (long)MLR * HH) return;
    int h = (int)(idx % HH);
    msgx[idx] = fmaxf(node[idx + HH] + gbias[h], 0.0f);
}

__global__ void h0_kernel(const float* __restrict__ node, float* __restrict__ hf)
{
    int idx = blockIdx.x * blockDim.x + threadIdx.x;
    if (idx >= MMOL * HH) return;
    int m = idx / HH;
    int h = idx - m * HH;
    long base = (long)(1 + m * LATM) * HH + h;
    float mx = -INFINITY;
    for (int t = 0; t < LATM; ++t) mx = fmaxf(mx, node[base + (long)t * HH]);
    hf[idx] = mx;
}

// ---------------------------------------------------------------------------
// GRU scan v3 (proven): gi precomputed. 256 blocks, 2 mols/block, XCD-pinned
// dirs. gout written in-place into gi[t][0:300].
// ---------------------------------------------------------------------------
__global__ __launch_bounds__(1024)
void gru_scan3(const float* __restrict__ WhhT_f, const float* __restrict__ bhh_f,
               const float* __restrict__ WhhT_b, const float* __restrict__ bhh_b,
               const float* __restrict__ h0, float* __restrict__ gi_f,
               float* __restrict__ gi_b)
{
    const int bid  = blockIdx.x;
    const int xcd  = bid & 7;
    const int dir  = (xcd >= 4) ? 1 : 0;
    const int rank = (bid >> 3) * 4 + (xcd & 3);   // 0..127, bijective per dir
    const int m0   = rank * 2;
    const float* WhhT = dir ? WhhT_b : WhhT_f;
    const float* bhh  = dir ? bhh_b  : bhh_f;
    float*       gi   = dir ? gi_b   : gi_f;
    const int tid = threadIdx.x;

    __shared__ float hs[2][304];
    __shared__ float ghs[2][H3];

    float bb = (tid < H3) ? bhh[tid] : 0.0f;

    for (int i = tid; i < 150; i += 1024) {
        int mm = i / 75, q = (i - mm * 75) * 4;
        *(float4*)&hs[mm][q] = *(const float4*)&h0[(long)(m0 + mm) * HH + q];
    }
    __syncthreads();

    for (int s = 0; s < LATM; ++s) {
        const int t = dir ? (LATM - 1 - s) : s;

        if (tid < H3) {
            float a0 = 0.0f, a1 = 0.0f;
            const float* wh = WhhT + tid;
#pragma unroll 4
            for (int k0 = 0; k0 < HH; k0 += 4) {
                float w0 = wh[(long)(k0 + 0) * H3];
                float w1 = wh[(long)(k0 + 1) * H3];
                float w2 = wh[(long)(k0 + 2) * H3];
                float w3 = wh[(long)(k0 + 3) * H3];
                float4 h0v = *(const float4*)&hs[0][k0];
                float4 h1v = *(const float4*)&hs[1][k0];
                a0 += h0v.x * w0 + h0v.y * w1 + h0v.z * w2 + h0v.w * w3;
                a1 += h1v.x * w0 + h1v.y * w1 + h1v.z * w2 + h1v.w * w3;
            }
            ghs[0][tid] = a0 + bb;
            ghs[1][tid] = a1 + bb;
        }
        __syncthreads();

        if (tid < 2 * HH) {
            int mm = tid / HH, hh = tid - mm * HH;
            long row = (long)(m0 + mm) * LATM + t;
            float* g = gi + row * H3;
            float ir = g[hh], iz = g[HH + hh], inn = g[2 * HH + hh];
            float r  = sigm(ir + ghs[mm][hh]);
            float z  = sigm(iz + ghs[mm][HH + hh]);
            float nn = tanhf(inn + r * ghs[mm][2 * HH + hh]);
            float hn = (1.0f - z) * nn + z * hs[mm][hh];
            hs[mm][hh] = hn;
            g[hh] = hn;
        }
        __syncthreads();
    }
}

__global__ void mean_kernel(const float* __restrict__ ah, float* __restrict__ out)
{
    int idx = blockIdx.x * blockDim.x + threadIdx.x;
    if (idx >= MMOL * HH) return;
    int m = idx / HH;
    int j = idx - m * HH;
    long base = (long)m * LATM * HH + j;
    float s = 0.0f;
    for (int t = 0; t < LATM; ++t) s += ah[base + (long)t * HH];
    out[idx] = s * (1.0f / LATM);
}

// ---------------------------------------------------------------------------
static inline int cdiv(long a, long b) { return (int)((a + b - 1) / b); }

extern "C" void kernel_launch(void* const* d_in, const int* in_sizes, int n_in,
                              void* d_out, int out_size, void* d_ws, size_t ws_size,
                              hipStream_t stream)
{
    const float* f_atoms  = (const float*)d_in[0];
    const float* f_bonds  = (const float*)d_in[1];
    const int*   a2b      = (const int*)d_in[2];
    const int*   b2a      = (const int*)d_in[3];
    const int*   b2revb   = (const int*)d_in[4];
    const float* W_i_atom = (const float*)d_in[5];
    const float* W_i_bond = (const float*)d_in[6];
    const float* W_h0     = (const float*)d_in[7];
    const float* W_h1     = (const float*)d_in[8];
    const float* W_lr     = (const float*)d_in[9];
    const float* gru_bias = (const float*)d_in[10];
    const float* Wih_f    = (const float*)d_in[11];
    const float* Whh_f    = (const float*)d_in[12];
    const float* bih_f    = (const float*)d_in[13];
    const float* bhh_f    = (const float*)d_in[14];
    const float* Wih_b    = (const float*)d_in[15];
    const float* Whh_b    = (const float*)d_in[16];
    const float* bih_b    = (const float*)d_in[17];
    const float* bhh_b    = (const float*)d_in[18];
    const float* W_o      = (const float*)d_in[19];
    const float* b_o      = (const float*)d_in[20];
    float* out = (float*)d_out;

    // fp32 arena (total 295,530,016 <= proven ws floor).
    // Depth-loop regions: P@0, S@157287600, MA@235931408, TH@275254208,
    // HFB@294915616. Scan overlays: gi_f@0, gi_b@117964800, msgx/AH in MA,
    // h0 + WhhT_f/b in TH.
    const size_t NEED = 295530016;
    if (ws_size < NEED) return;

    char* b = (char*)d_ws;
    float* P   = (float*)b;
    float* S   = (float*)(b + 157287600);
    float* MA  = (float*)(b + 235931408);
    float* TH  = (float*)(b + 275254208);

    float* Pia  = P + (size_t)AA * HH;        // ia_rc [A,300]
    float* giF  = (float*)b;                  // [ML,900]
    float* giB  = (float*)(b + 117964800);    // [ML,900]
    float* MSGX = MA;                         // [ML,300] (MA dead post-node)
    float* AH   = MA;                         // atomhid [ML,300]
    float* H0   = TH;                         // [M,300]
    float* WhhT_f = TH + 76800;               // 270,000 floats
    float* WhhT_b = TH + 346800;              // 270,000 floats

    dim3 blk(256);
    const int gA = cdiv((long)AA * HH, 256);
    dim3 gmA (cdiv(AA, 128),   cdiv(HH, 64));
    dim3 gmB3(cdiv(BBND, 128), cdiv(HH, 64));
    dim3 gmB1(cdiv(BBND, 128), cdiv(150, 64));
    dim3 gmT (cdiv(AA, 128),   cdiv(150, 64));
    dim3 gmG (cdiv(MLR, 128),  cdiv(H3, 64));
    dim3 gmO (cdiv(MLR, 128),  cdiv(HH, 64));

    // 1. ma = input_atom ; 2. mb0 = input_bond -> P
    gemm_big<true, false, false><<<gmA, blk, 0, stream>>>(
        f_atoms, AFD, W_i_atom, AFD, nullptr, MA, AA, HH, AFD);
    gemm_big<true, false, false><<<gmB3, blk, 0, stream>>>(
        f_bonds, BFD, W_i_bond, BFD, nullptr, P, BBND, HH, BFD);

    // Depth loop
    const float* Wh[2] = { W_h0, W_h1 };
    for (int d = 0; d < 2; ++d) {
        const float* W = Wh[d];
        aggregate<true><<<gA, blk, 0, stream>>>(P, a2b, MA);
        gemm_big<false, false, false><<<gmB1, blk, 0, stream>>>(
            P, HH, W, HH, nullptr, S, BBND, 150, HH);
        vw_hi_gemm<<<cdiv(BBND, 128), blk, 0, stream>>>(P, W, BBND);
        gemm_big<false, false, false><<<gmT, blk, 0, stream>>>(
            MA, HH, W + 150 * HH, HH, nullptr, TH, AA, 150, HH);
        bond_half<<<gmB1, blk, 0, stream>>>(
            f_bonds, W_i_bond, TH, P, 300, b2a, b2revb, P, 150, BBND);
        gemm_big<false, false, false><<<gmT, blk, 0, stream>>>(
            MA, HH, W, HH, nullptr, TH, AA, 150, HH);
        bond_half<<<gmB1, blk, 0, stream>>>(
            f_bonds, W_i_bond, TH, S, 150, b2a, b2revb, P, 0, BBND);
    }

    // Final aggregation -> S
    aggregate<false><<<gA, blk, 0, stream>>>(P, a2b, S);

    // ia recomputed -> Pia ; node -> P[0:A*300)
    gemm_big<true, false, false><<<gmA, blk, 0, stream>>>(
        f_atoms, AFD, W_i_atom, AFD, nullptr, Pia, AA, HH, AFD);
    gemm_big<false, false, false><<<gmA, blk, 0, stream>>>(
        S,   HH, W_lr,          H3, nullptr, P, AA, HH, HH);
    gemm_big<false, false, true><<<gmA, blk, 0, stream>>>(
        MA,  HH, W_lr + HH,     H3, nullptr, P, AA, HH, HH);
    gemm_big<false, false, true><<<gmA, blk, 0, stream>>>(
        Pia, HH, W_lr + 2 * HH, H3, nullptr, P, AA, HH, HH);

    // GRU prep: msgx -> MA region, h0 -> TH, WhhT transposes -> TH
    msgx_kernel<<<cdiv((long)MLR * HH, 256), blk, 0, stream>>>(P, gru_bias, MSGX);
    h0_kernel<<<cdiv(MMOL * HH, 256), blk, 0, stream>>>(P, H0);
    transpose_kernel<<<cdiv(270000, 256), blk, 0, stream>>>(Whh_f, WhhT_f, H3, HH);
    transpose_kernel<<<cdiv(270000, 256), blk, 0, stream>>>(Whh_b, WhhT_b, H3, HH);

    // gi = msgx @ Wih^T + bih (both dirs; overwrites node/mb/agg — all dead)
    gemm_big<false, true, false><<<gmG, blk, 0, stream>>>(
        MSGX, HH, Wih_f, HH, bih_f, giF, MLR, H3, HH);
    gemm_big<false, true, false><<<gmG, blk, 0, stream>>>(
        MSGX, HH, Wih_b, HH, bih_b, giB, MLR, H3, HH);

    // Fused bidirectional scan (gout in-place into gi[t][0:300])
    gru_scan3<<<dim3(256), dim3(1024), 0, stream>>>(
        WhhT_f, bhh_f, WhhT_b, bhh_b, H0, giF, giB);

    // atom_hiddens = relu(gout_f@Wo_lo^T + gout_b@Wo_hi^T + b_o) -> AH
    gemm_big<false, false, false><<<gmO, blk, 0, stream>>>(
        giF, H3, W_o,      2 * HH, nullptr, AH, MLR, HH, HH);
    gemm_big<true, true, true><<<gmO, blk, 0, stream>>>(
        giB, H3, W_o + HH, 2 * HH, b_o,     AH, MLR, HH, HH);

    // mol_vecs -> out
    mean_kernel<<<cdiv(MMOL * HH, 256), blk, 0, stream>>>(AH, out);
}

// Round 11
// 5206.232 us; speedup vs baseline: 1.3952x; 1.0803x over previous
//
#include <hip/hip_runtime.h>
#include <math.h>

// Problem constants
#define HH   300
#define H3   900
#define MMOL 256
#define LATM 128
#define AA   32769        // 1 + 256*128
#define NBB  6
#define BBND 131073       // 1 + 4*256*128
#define AFD  133
#define BFD  147
#define MLR  (MMOL * LATM)   // 32768

static __device__ __forceinline__ float sigm(float x) { return 1.0f / (1.0f + expf(-x)); }

// ---------------------------------------------------------------------------
// Tiled fp32 GEMM, 128x64 tile, BK=16, 8x4 microtile, 256 threads.
// Register-prefetch double-buffer: next tile's global loads issue before the
// compute block, hiding global latency under FMAs. Same math/order as before.
// ---------------------------------------------------------------------------
template<bool RELU, bool BIAS, bool ACCUM>
__global__ __launch_bounds__(256)
void gemm_big(const float* __restrict__ X, int ldx, const float* __restrict__ W, int ldw,
              const float* __restrict__ Bias, float* __restrict__ C,
              int rows, int N, int K)
{
    __shared__ float Xs[16][132];
    __shared__ float Ws[16][68];
    const int row0 = blockIdx.x * 128;
    const int col0 = blockIdx.y * 64;
    const int tid  = threadIdx.x;
    const int tm   = (tid >> 4) * 8;
    const int tn   = (tid & 15) * 4;
    const bool xv  = ((ldx & 3) == 0);
    const bool wv  = ((ldw & 3) == 0);

    float px[2][4], pw[4];

    auto loadTile = [&](int k0) {
        const int rem = K - k0;
#pragma unroll
        for (int l = 0; l < 2; ++l) {
            int s = tid + l * 256;
            int r = s >> 2, kq = (s & 3) * 4;
            int gr = row0 + r;
            float v0 = 0, v1 = 0, v2 = 0, v3 = 0;
            if (gr < rows) {
                const float* xp = X + (long)gr * ldx + k0 + kq;
                if (xv && rem >= 16) {
                    float4 t4 = *(const float4*)xp;
                    v0 = t4.x; v1 = t4.y; v2 = t4.z; v3 = t4.w;
                } else {
                    if (kq + 0 < rem) v0 = xp[0];
                    if (kq + 1 < rem) v1 = xp[1];
                    if (kq + 2 < rem) v2 = xp[2];
                    if (kq + 3 < rem) v3 = xp[3];
                }
            }
            px[l][0] = v0; px[l][1] = v1; px[l][2] = v2; px[l][3] = v3;
        }
        {
            int r = tid >> 2, kq = (tid & 3) * 4;
            int gc = col0 + r;
            float v0 = 0, v1 = 0, v2 = 0, v3 = 0;
            if (gc < N) {
                const float* wp = W + (long)gc * ldw + k0 + kq;
                if (wv && rem >= 16) {
                    float4 t4 = *(const float4*)wp;
                    v0 = t4.x; v1 = t4.y; v2 = t4.z; v3 = t4.w;
                } else {
                    if (kq + 0 < rem) v0 = wp[0];
                    if (kq + 1 < rem) v1 = wp[1];
                    if (kq + 2 < rem) v2 = wp[2];
                    if (kq + 3 < rem) v3 = wp[3];
                }
            }
            pw[0] = v0; pw[1] = v1; pw[2] = v2; pw[3] = v3;
        }
    };
    auto commitTile = [&]() {
#pragma unroll
        for (int l = 0; l < 2; ++l) {
            int s = tid + l * 256;
            int r = s >> 2, kq = (s & 3) * 4;
            Xs[kq + 0][r] = px[l][0]; Xs[kq + 1][r] = px[l][1];
            Xs[kq + 2][r] = px[l][2]; Xs[kq + 3][r] = px[l][3];
        }
        {
            int r = tid >> 2, kq = (tid & 3) * 4;
            Ws[kq + 0][r] = pw[0]; Ws[kq + 1][r] = pw[1];
            Ws[kq + 2][r] = pw[2]; Ws[kq + 3][r] = pw[3];
        }
    };

    float acc[8][4];
#pragma unroll
    for (int i = 0; i < 8; ++i)
#pragma unroll
        for (int j = 0; j < 4; ++j) acc[i][j] = 0.0f;

    loadTile(0);
    for (int k0 = 0; k0 < K; k0 += 16) {
        commitTile();
        __syncthreads();
        if (k0 + 16 < K) loadTile(k0 + 16);
#pragma unroll
        for (int kk = 0; kk < 16; ++kk) {
            float4 xa = *(const float4*)&Xs[kk][tm];
            float4 xb = *(const float4*)&Xs[kk][tm + 4];
            float4 wq = *(const float4*)&Ws[kk][tn];
            float xr[8] = {xa.x, xa.y, xa.z, xa.w, xb.x, xb.y, xb.z, xb.w};
            float wr[4] = {wq.x, wq.y, wq.z, wq.w};
#pragma unroll
            for (int i = 0; i < 8; ++i)
#pragma unroll
                for (int j = 0; j < 4; ++j)
                    acc[i][j] += xr[i] * wr[j];
        }
        __syncthreads();
    }

#pragma unroll
    for (int i = 0; i < 8; ++i) {
        int gr = row0 + tm + i;
        if (gr >= rows) continue;
#pragma unroll
        for (int j = 0; j < 4; ++j) {
            int gc = col0 + tn + j;
            if (gc >= N) continue;
            float v = acc[i][j];
            if (BIAS)  v += Bias[gc];
            if (ACCUM) v += C[(long)gr * N + gc];
            if (RELU)  v = fmaxf(v, 0.0f);
            C[(long)gr * N + gc] = v;
        }
    }
}

// transposeQ: Whh[900][300] -> WQ[(k/4)][n][4]  (float4-loadable per gate n)
__global__ void transposeQ(const float* __restrict__ in, float* __restrict__ out)
{
    long idx = (long)blockIdx.x * blockDim.x + threadIdx.x;
    if (idx >= 270000) return;
    int n = (int)(idx / 300), k = (int)(idx - (long)n * 300);
    out[(long)(k >> 2) * 3600 + n * 4 + (k & 3)] = in[idx];
}

// ---------------------------------------------------------------------------
// vw_hi_gemm: in-place staged GEMM (proven round-10 win).
//   P[r, 0:150) = (P[r, 0:300) @ W^T)[:, 150:300)
// ---------------------------------------------------------------------------
__global__ __launch_bounds__(256)
void vw_hi_gemm(float* __restrict__ P, const float* __restrict__ W, int rows)
{
    __shared__ float Xs[16][132];
    __shared__ float Ws[16][192];
    const int row0 = blockIdx.x * 128;
    const int tid  = threadIdx.x;
    const int tm   = (tid >> 4) * 8;
    const int tn   = (tid & 15) * 4;

    float acc[8][12];
#pragma unroll
    for (int i = 0; i < 8; ++i)
#pragma unroll
        for (int j = 0; j < 12; ++j) acc[i][j] = 0.0f;

    for (int k0 = 0; k0 < 300; k0 += 16) {
        const int rem = 300 - k0;
#pragma unroll
        for (int l = 0; l < 2; ++l) {
            int s = tid + l * 256;
            int r = s >> 2, kq = (s & 3) * 4;
            int gr = row0 + r;
            float v0 = 0, v1 = 0, v2 = 0, v3 = 0;
            if (gr < rows) {
                const float* xp = P + (long)gr * 300 + k0 + kq;
                if (rem >= 16) {
                    float4 t4 = *(const float4*)xp;
                    v0 = t4.x; v1 = t4.y; v2 = t4.z; v3 = t4.w;
                } else {
                    if (kq + 0 < rem) v0 = xp[0];
                    if (kq + 1 < rem) v1 = xp[1];
                    if (kq + 2 < rem) v2 = xp[2];
                    if (kq + 3 < rem) v3 = xp[3];
                }
            }
            Xs[kq + 0][r] = v0; Xs[kq + 1][r] = v1;
            Xs[kq + 2][r] = v2; Xs[kq + 3][r] = v3;
        }
        for (int s = tid; s < 600; s += 256) {
            int r = s >> 2, kq = (s & 3) * 4;
            const float* wp = W + (long)(150 + r) * 300 + k0 + kq;
            float v0 = 0, v1 = 0, v2 = 0, v3 = 0;
            if (rem >= 16) {
                float4 t4 = *(const float4*)wp;
                v0 = t4.x; v1 = t4.y; v2 = t4.z; v3 = t4.w;
            } else {
                if (kq + 0 < rem) v0 = wp[0];
                if (kq + 1 < rem) v1 = wp[1];
                if (kq + 2 < rem) v2 = wp[2];
                if (kq + 3 < rem) v3 = wp[3];
            }
            Ws[kq + 0][r] = v0; Ws[kq + 1][r] = v1;
            Ws[kq + 2][r] = v2; Ws[kq + 3][r] = v3;
        }
        __syncthreads();
#pragma unroll
        for (int kk = 0; kk < 16; ++kk) {
            float4 xa = *(const float4*)&Xs[kk][tm];
            float4 xb = *(const float4*)&Xs[kk][tm + 4];
            float4 w0 = *(const float4*)&Ws[kk][tn];
            float4 w1 = *(const float4*)&Ws[kk][tn + 64];
            float4 w2 = *(const float4*)&Ws[kk][tn + 128];
            float xr[8] = {xa.x, xa.y, xa.z, xa.w, xb.x, xb.y, xb.z, xb.w};
            float wr[12] = {w0.x, w0.y, w0.z, w0.w, w1.x, w1.y, w1.z, w1.w,
                            w2.x, w2.y, w2.z, w2.w};
#pragma unroll
            for (int i = 0; i < 8; ++i)
#pragma unroll
                for (int j = 0; j < 12; ++j)
                    acc[i][j] += xr[i] * wr[j];
        }
        __syncthreads();
    }

#pragma unroll
    for (int i = 0; i < 8; ++i) {
        int gr = row0 + tm + i;
        if (gr >= rows) continue;
#pragma unroll
        for (int c = 0; c < 3; ++c)
#pragma unroll
            for (int j = 0; j < 4; ++j) {
                int cn = tn + c * 64 + j;
                if (cn < 150) P[(long)gr * 300 + cn] = acc[i][c * 4 + j];
            }
    }
}

// ---------------------------------------------------------------------------
// Half-column bond update (128x64 tiles, K=147 recomputed input_bond)
// ---------------------------------------------------------------------------
__global__ __launch_bounds__(256)
void bond_half(const float* __restrict__ FB, const float* __restrict__ WiB,
               const float* __restrict__ Th, const float* __restrict__ Vsrc, int vstride,
               const int* __restrict__ b2a, const int* __restrict__ b2revb,
               float* __restrict__ P, int c0, int rows)
{
    __shared__ float Xs[16][132];
    __shared__ float Ws[16][68];
    __shared__ int ra[128], rb[128];
    const int row0 = blockIdx.x * 128;
    const int col0 = blockIdx.y * 64;
    const int tid  = threadIdx.x;

    if (tid < 128) {
        int gr = row0 + tid;
        ra[tid] = (gr < rows) ? b2a[gr] : 0;
    } else {
        int m = tid - 128;
        int gr = row0 + m;
        rb[m] = (gr < rows) ? b2revb[gr] : 0;
    }

    const int tm = (tid >> 4) * 8;
    const int tn = (tid & 15) * 4;
    float acc[8][4];
#pragma unroll
    for (int i = 0; i < 8; ++i)
#pragma unroll
        for (int j = 0; j < 4; ++j) acc[i][j] = 0.0f;

    for (int k0 = 0; k0 < BFD; k0 += 16) {
        const int rem = BFD - k0;
#pragma unroll
        for (int l = 0; l < 2; ++l) {
            int s = tid + l * 256;
            int r = s >> 2, kq = (s & 3) * 4;
            int gr = row0 + r;
            float v0 = 0, v1 = 0, v2 = 0, v3 = 0;
            if (gr < rows) {
                const float* xp = FB + (long)gr * BFD + k0 + kq;
                if (kq + 0 < rem) v0 = xp[0];
                if (kq + 1 < rem) v1 = xp[1];
                if (kq + 2 < rem) v2 = xp[2];
                if (kq + 3 < rem) v3 = xp[3];
            }
            Xs[kq + 0][r] = v0; Xs[kq + 1][r] = v1;
            Xs[kq + 2][r] = v2; Xs[kq + 3][r] = v3;
        }
        {
            int r = tid >> 2, kq = (tid & 3) * 4;
            int gc = col0 + r;
            float v0 = 0, v1 = 0, v2 = 0, v3 = 0;
            if (gc < 150) {
                const float* wp = WiB + (long)(c0 + gc) * BFD + k0 + kq;
                if (kq + 0 < rem) v0 = wp[0];
                if (kq + 1 < rem) v1 = wp[1];
                if (kq + 2 < rem) v2 = wp[2];
                if (kq + 3 < rem) v3 = wp[3];
            }
            Ws[kq + 0][r] = v0; Ws[kq + 1][r] = v1;
            Ws[kq + 2][r] = v2; Ws[kq + 3][r] = v3;
        }
        __syncthreads();
#pragma unroll
        for (int kk = 0; kk < 16; ++kk) {
            float4 xa = *(const float4*)&Xs[kk][tm];
            float4 xb = *(const float4*)&Xs[kk][tm + 4];
            float4 wq = *(const float4*)&Ws[kk][tn];
            float xr[8] = {xa.x, xa.y, xa.z, xa.w, xb.x, xb.y, xb.z, xb.w};
            float wr[4] = {wq.x, wq.y, wq.z, wq.w};
#pragma unroll
            for (int i = 0; i < 8; ++i)
#pragma unroll
                for (int j = 0; j < 4; ++j)
                    acc[i][j] += xr[i] * wr[j];
        }
        __syncthreads();
    }

#pragma unroll
    for (int i = 0; i < 8; ++i) {
        int gr = row0 + tm + i;
        if (gr >= rows) continue;
        int a  = ra[tm + i];
        int rv = rb[tm + i];
#pragma unroll
        for (int j = 0; j < 4; ++j) {
            int cn = col0 + tn + j;
            if (cn >= 150) continue;
            float ib = fmaxf(acc[i][j], 0.0f);
            float v  = ib + Th[(long)a * 150 + cn] - Vsrc[(long)rv * vstride + cn];
            P[(long)gr * 300 + c0 + cn] = fmaxf(v, 0.0f);
        }
    }
}

template<bool ADD>
__global__ void aggregate(const float* __restrict__ mb, const int* __restrict__ a2b,
                          float* __restrict__ dst)
{
    long idx = (long)blockIdx.x * blockDim.x + threadIdx.x;
    if (idx >= (long)AA * HH) return;
    int a = (int)(idx / HH);
    int h = (int)(idx - (long)a * HH);
    const int* nb = a2b + (long)a * NBB;
    float s = 0.0f, mx = -INFINITY;
#pragma unroll
    for (int i = 0; i < NBB; ++i) {
        float v = mb[(long)nb[i] * HH + h];
        s += v;
        mx = fmaxf(mx, v);
    }
    float r = s * mx;
    if (ADD) r += dst[idx];
    dst[idx] = r;
}

__global__ void msgx_kernel(const float* __restrict__ node, const float* __restrict__ gbias,
                            float* __restrict__ msgx)
{
    long idx = (long)blockIdx.x * blockDim.x + threadIdx.x;
    if (idx >= (long)MLR * HH) return;
    int h = (int)(idx % HH);
    msgx[idx] = fmaxf(node[idx + HH] + gbias[h], 0.0f);
}

__global__ void h0_kernel(const float* __restrict__ node, float* __restrict__ hf)
{
    int idx = blockIdx.x * blockDim.x + threadIdx.x;
    if (idx >= MMOL * HH) return;
    int m = idx / HH;
    int h = idx - m * HH;
    long base = (long)(1 + m * LATM) * HH + h;
    float mx = -INFINITY;
    for (int t = 0; t < LATM; ++t) mx = fmaxf(mx, node[base + (long)t * HH]);
    hf[idx] = mx;
}

// ---------------------------------------------------------------------------
// GRU scan v3q: as proven v3 (256 blocks, 2 mols, XCD-pinned dirs) but the
// recurrent weights are in interleaved WQ[k/4][n][4] layout: one coalesced
// float4 load replaces 4 scalar stride-900 loads per 4-k chunk.
// ---------------------------------------------------------------------------
__global__ __launch_bounds__(1024)
void gru_scan3(const float* __restrict__ WQ_f, const float* __restrict__ bhh_f,
               const float* __restrict__ WQ_b, const float* __restrict__ bhh_b,
               const float* __restrict__ h0, float* __restrict__ gi_f,
               float* __restrict__ gi_b)
{
    const int bid  = blockIdx.x;
    const int xcd  = bid & 7;
    const int dir  = (xcd >= 4) ? 1 : 0;
    const int rank = (bid >> 3) * 4 + (xcd & 3);   // 0..127, bijective per dir
    const int m0   = rank * 2;
    const float* WQ  = dir ? WQ_b  : WQ_f;
    const float* bhh = dir ? bhh_b : bhh_f;
    float*       gi  = dir ? gi_b  : gi_f;
    const int tid = threadIdx.x;

    __shared__ float hs[2][304];
    __shared__ float ghs[2][H3];

    float bb = (tid < H3) ? bhh[tid] : 0.0f;

    for (int i = tid; i < 150; i += 1024) {
        int mm = i / 75, q = (i - mm * 75) * 4;
        *(float4*)&hs[mm][q] = *(const float4*)&h0[(long)(m0 + mm) * HH + q];
    }
    __syncthreads();

    for (int s = 0; s < LATM; ++s) {
        const int t = dir ? (LATM - 1 - s) : s;

        if (tid < H3) {
            float a0 = 0.0f, a1 = 0.0f;
            const float* wq = WQ + (long)tid * 4;
#pragma unroll 4
            for (int k0 = 0; k0 < HH; k0 += 4) {
                float4 w = *(const float4*)wq;
                wq += 3600;
                float4 h0v = *(const float4*)&hs[0][k0];
                float4 h1v = *(const float4*)&hs[1][k0];
                a0 += h0v.x * w.x + h0v.y * w.y + h0v.z * w.z + h0v.w * w.w;
                a1 += h1v.x * w.x + h1v.y * w.y + h1v.z * w.z + h1v.w * w.w;
            }
            ghs[0][tid] = a0 + bb;
            ghs[1][tid] = a1 + bb;
        }
        __syncthreads();

        if (tid < 2 * HH) {
            int mm = tid / HH, hh = tid - mm * HH;
            long row = (long)(m0 + mm) * LATM + t;
            float* g = gi + row * H3;
            float ir = g[hh], iz = g[HH + hh], inn = g[2 * HH + hh];
            float r  = sigm(ir + ghs[mm][hh]);
            float z  = sigm(iz + ghs[mm][HH + hh]);
            float nn = tanhf(inn + r * ghs[mm][2 * HH + hh]);
            float hn = (1.0f - z) * nn + z * hs[mm][hh];
            hs[mm][hh] = hn;
            g[hh] = hn;
        }
        __syncthreads();
    }
}

__global__ void mean_kernel(const float* __restrict__ ah, float* __restrict__ out)
{
    int idx = blockIdx.x * blockDim.x + threadIdx.x;
    if (idx >= MMOL * HH) return;
    int m = idx / HH;
    int j = idx - m * HH;
    long base = (long)m * LATM * HH + j;
    float s = 0.0f;
    for (int t = 0; t < LATM; ++t) s += ah[base + (long)t * HH];
    out[idx] = s * (1.0f / LATM);
}

// ---------------------------------------------------------------------------
static inline int cdiv(long a, long b) { return (int)((a + b - 1) / b); }

extern "C" void kernel_launch(void* const* d_in, const int* in_sizes, int n_in,
                              void* d_out, int out_size, void* d_ws, size_t ws_size,
                              hipStream_t stream)
{
    const float* f_atoms  = (const float*)d_in[0];
    const float* f_bonds  = (const float*)d_in[1];
    const int*   a2b      = (const int*)d_in[2];
    const int*   b2a      = (const int*)d_in[3];
    const int*   b2revb   = (const int*)d_in[4];
    const float* W_i_atom = (const float*)d_in[5];
    const float* W_i_bond = (const float*)d_in[6];
    const float* W_h0     = (const float*)d_in[7];
    const float* W_h1     = (const float*)d_in[8];
    const float* W_lr     = (const float*)d_in[9];
    const float* gru_bias = (const float*)d_in[10];
    const float* Wih_f    = (const float*)d_in[11];
    const float* Whh_f    = (const float*)d_in[12];
    const float* bih_f    = (const float*)d_in[13];
    const float* bhh_f    = (const float*)d_in[14];
    const float* Wih_b    = (const float*)d_in[15];
    const float* Whh_b    = (const float*)d_in[16];
    const float* bih_b    = (const float*)d_in[17];
    const float* bhh_b    = (const float*)d_in[18];
    const float* W_o      = (const float*)d_in[19];
    const float* b_o      = (const float*)d_in[20];
    float* out = (float*)d_out;

    // fp32 arena (total 295,530,016 <= proven ws floor).
    // Depth-loop regions: P@0, S@157287600, MA@235931408, TH@275254208.
    // Scan overlays: gi_f@0, gi_b@117964800, msgx/AH in MA, h0 + WQ_f/b in TH.
    const size_t NEED = 295530016;
    if (ws_size < NEED) return;

    char* b = (char*)d_ws;
    float* P   = (float*)b;
    float* S   = (float*)(b + 157287600);
    float* MA  = (float*)(b + 235931408);
    float* TH  = (float*)(b + 275254208);

    float* Pia  = P + (size_t)AA * HH;        // ia_rc [A,300]
    float* giF  = (float*)b;                  // [ML,900]
    float* giB  = (float*)(b + 117964800);    // [ML,900]
    float* MSGX = MA;                         // [ML,300] (MA dead post-node)
    float* AH   = MA;                         // atomhid [ML,300]
    float* H0   = TH;                         // [M,300]
    float* WQ_f = TH + 76800;                 // 270,000 floats
    float* WQ_b = TH + 346800;                // 270,000 floats

    dim3 blk(256);
    const int gA = cdiv((long)AA * HH, 256);
    dim3 gmA (cdiv(AA, 128),   cdiv(HH, 64));
    dim3 gmB3(cdiv(BBND, 128), cdiv(HH, 64));
    dim3 gmB1(cdiv(BBND, 128), cdiv(150, 64));
    dim3 gmT (cdiv(AA, 128),   cdiv(150, 64));
    dim3 gmG (cdiv(MLR, 128),  cdiv(H3, 64));
    dim3 gmO (cdiv(MLR, 128),  cdiv(HH, 64));

    // 1. ma = input_atom ; 2. mb0 = input_bond -> P
    gemm_big<true, false, false><<<gmA, blk, 0, stream>>>(
        f_atoms, AFD, W_i_atom, AFD, nullptr, MA, AA, HH, AFD);
    gemm_big<true, false, false><<<gmB3, blk, 0, stream>>>(
        f_bonds, BFD, W_i_bond, BFD, nullptr, P, BBND, HH, BFD);

    // Depth loop
    const float* Wh[2] = { W_h0, W_h1 };
    for (int d = 0; d < 2; ++d) {
        const float* W = Wh[d];
        aggregate<true><<<gA, blk, 0, stream>>>(P, a2b, MA);
        gemm_big<false, false, false><<<gmB1, blk, 0, stream>>>(
            P, HH, W, HH, nullptr, S, BBND, 150, HH);
        vw_hi_gemm<<<cdiv(BBND, 128), blk, 0, stream>>>(P, W, BBND);
        gemm_big<false, false, false><<<gmT, blk, 0, stream>>>(
            MA, HH, W + 150 * HH, HH, nullptr, TH, AA, 150, HH);
        bond_half<<<gmB1, blk, 0, stream>>>(
            f_bonds, W_i_bond, TH, P, 300, b2a, b2revb, P, 150, BBND);
        gemm_big<false, false, false><<<gmT, blk, 0, stream>>>(
            MA, HH, W, HH, nullptr, TH, AA, 150, HH);
        bond_half<<<gmB1, blk, 0, stream>>>(
            f_bonds, W_i_bond, TH, S, 150, b2a, b2revb, P, 0, BBND);
    }

    // Final aggregation -> S
    aggregate<false><<<gA, blk, 0, stream>>>(P, a2b, S);

    // ia recomputed -> Pia ; node -> P[0:A*300)
    gemm_big<true, false, false><<<gmA, blk, 0, stream>>>(
        f_atoms, AFD, W_i_atom, AFD, nullptr, Pia, AA, HH, AFD);
    gemm_big<false, false, false><<<gmA, blk, 0, stream>>>(
        S,   HH, W_lr,          H3, nullptr, P, AA, HH, HH);
    gemm_big<false, false, true><<<gmA, blk, 0, stream>>>(
        MA,  HH, W_lr + HH,     H3, nullptr, P, AA, HH, HH);
    gemm_big<false, false, true><<<gmA, blk, 0, stream>>>(
        Pia, HH, W_lr + 2 * HH, H3, nullptr, P, AA, HH, HH);

    // GRU prep: msgx -> MA region, h0 -> TH, WQ interleaved transposes -> TH
    msgx_kernel<<<cdiv((long)MLR * HH, 256), blk, 0, stream>>>(P, gru_bias, MSGX);
    h0_kernel<<<cdiv(MMOL * HH, 256), blk, 0, stream>>>(P, H0);
    transposeQ<<<cdiv(270000, 256), blk, 0, stream>>>(Whh_f, WQ_f);
    transposeQ<<<cdiv(270000, 256), blk, 0, stream>>>(Whh_b, WQ_b);

    // gi = msgx @ Wih^T + bih (both dirs; overwrites node/mb/agg — all dead)
    gemm_big<false, true, false><<<gmG, blk, 0, stream>>>(
        MSGX, HH, Wih_f, HH, bih_f, giF, MLR, H3, HH);
    gemm_big<false, true, false><<<gmG, blk, 0, stream>>>(
        MSGX, HH, Wih_b, HH, bih_b, giB, MLR, H3, HH);

    // Fused bidirectional scan (gout in-place into gi[t][0:300])
    gru_scan3<<<dim3(256), dim3(1024), 0, stream>>>(
        WQ_f, bhh_f, WQ_b, bhh_b, H0, giF, giB);

    // atom_hiddens = relu(gout_f@Wo_lo^T + gout_b@Wo_hi^T + b_o) -> AH
    gemm_big<false, false, false><<<gmO, blk, 0, stream>>>(
        giF, H3, W_o,      2 * HH, nullptr, AH, MLR, HH, HH);
    gemm_big<true, true, true><<<gmO, blk, 0, stream>>>(
        giB, H3, W_o + HH, 2 * HH, b_o,     AH, MLR, HH, HH);

    // mol_vecs -> out
    mean_kernel<<<cdiv(MMOL * HH, 256), blk, 0, stream>>>(AH, out);
}